// Round 1
// baseline (872.378 us; speedup 1.0000x reference)
//
#include <hip/hip_runtime.h>
#include <math.h>

// Problem constants
constexpr int LQ  = 1024;   // sequence length
constexpr int NH  = 32;     // heads
constexpr int HDM = 64;     // head dim
constexpr int FDM = 64;     // feature dim
constexpr int HID = 2048;   // NH*HDM
constexpr int NCH = 16;     // chunks
constexpr int CT  = 64;     // chunk length (NCH*CT == LQ)
#define EPSV 1e-12f

// ---------------------------------------------------------------------------
// GEMM (NT): C[M,N] = A[M,K] * B[N,K]^T, all row-major fp32.
// 64x64 tile, BK=16, 256 threads, 4x4 microtile, k-major LDS fragments.
// ---------------------------------------------------------------------------
__global__ __launch_bounds__(256) void gemm_nt(const float* __restrict__ A,
                                               const float* __restrict__ Bm,
                                               float* __restrict__ C,
                                               int M, int N, int K) {
    __shared__ float As[16][64];   // [k][m]
    __shared__ float Bs[16][64];   // [k][n]
    const int t  = threadIdx.x;
    const int tx = t & 15;         // n-tile
    const int ty = t >> 4;         // m-tile
    const int bm = blockIdx.y * 64;
    const int bn = blockIdx.x * 64;

    const int lr = t >> 2;         // load row 0..63
    const int lc = (t & 3) * 4;    // load k-offset 0,4,8,12

    float acc[4][4] = {};

    for (int k0 = 0; k0 < K; k0 += 16) {
        float4 av = *(const float4*)&A [(bm + lr) * K + k0 + lc];
        float4 bv = *(const float4*)&Bm[(bn + lr) * K + k0 + lc];
        __syncthreads();
        As[lc + 0][lr] = av.x; As[lc + 1][lr] = av.y;
        As[lc + 2][lr] = av.z; As[lc + 3][lr] = av.w;
        Bs[lc + 0][lr] = bv.x; Bs[lc + 1][lr] = bv.y;
        Bs[lc + 2][lr] = bv.z; Bs[lc + 3][lr] = bv.w;
        __syncthreads();
#pragma unroll
        for (int kk = 0; kk < 16; ++kk) {
            float4 a = *(const float4*)&As[kk][ty * 4];
            float4 b = *(const float4*)&Bs[kk][tx * 4];
            acc[0][0] += a.x * b.x; acc[0][1] += a.x * b.y; acc[0][2] += a.x * b.z; acc[0][3] += a.x * b.w;
            acc[1][0] += a.y * b.x; acc[1][1] += a.y * b.y; acc[1][2] += a.y * b.z; acc[1][3] += a.y * b.w;
            acc[2][0] += a.z * b.x; acc[2][1] += a.z * b.y; acc[2][2] += a.z * b.z; acc[2][3] += a.z * b.w;
            acc[3][0] += a.w * b.x; acc[3][1] += a.w * b.y; acc[3][2] += a.w * b.z; acc[3][3] += a.w * b.w;
        }
    }
#pragma unroll
    for (int i = 0; i < 4; ++i) {
        float4 o = make_float4(acc[i][0], acc[i][1], acc[i][2], acc[i][3]);
        *(float4*)&C[(bm + ty * 4 + i) * N + bn + tx * 4] = o;
    }
}

// ---------------------------------------------------------------------------
// Feature map: z[f] = sum_d X[l, h*64+d] * Wf[h, d, f]; softmax over f (64).
// grid (LQ, NH), block 64. Output layout [h][l][f].
// ---------------------------------------------------------------------------
__global__ __launch_bounds__(64) void feature_map(const float* __restrict__ X,
                                                  const float* __restrict__ Wf,
                                                  float* __restrict__ out) {
    const int l = blockIdx.x, h = blockIdx.y, f = threadIdx.x;
    __shared__ float xs[64];
    xs[f] = X[l * HID + h * HDM + f];
    __syncthreads();
    float z = 0.f;
    const float* w = Wf + h * HDM * FDM + f;
#pragma unroll 8
    for (int d = 0; d < HDM; ++d) z += xs[d] * w[d * FDM];
    float m = z;
#pragma unroll
    for (int off = 32; off; off >>= 1) m = fmaxf(m, __shfl_xor(m, off));
    float e = __expf(z - m);
    float s = e;
#pragma unroll
    for (int off = 32; off; off >>= 1) s += __shfl_xor(s, off);
    out[(h * LQ + l) * FDM + f] = e / s;
}

// ---------------------------------------------------------------------------
// Per-chunk inclusive sums: S_c[f][d] = sum_{l in chunk} fk[l,f]*v[l,d],
// Ks_c[f] = sum_{l in chunk} fk[l,f].  grid (NCH, NH), block 256.
// thread: d = lane, wave handles f-block of 16.
// ---------------------------------------------------------------------------
__global__ __launch_bounds__(256) void chunk_sums(const float* __restrict__ fk,
                                                  const float* __restrict__ V,
                                                  float* __restrict__ S,
                                                  float* __restrict__ Ks) {
    const int c = blockIdx.x, h = blockIdx.y;
    const int d = threadIdx.x & 63, fb = (threadIdx.x >> 6) * 16;
    const int l0 = c * CT;
    const float* fkh = fk + (h * LQ + l0) * FDM;
    const float* vh  = V + l0 * HID + h * HDM;
    float acc[16] = {};
    for (int l = 0; l < CT; ++l) {
        float vv = vh[l * HID + d];
        const float* fr = fkh + l * FDM + fb;
#pragma unroll
        for (int i = 0; i < 16; ++i) acc[i] += fr[i] * vv;
    }
    float* Sp = S + (h * NCH + c) * FDM * HDM;
#pragma unroll
    for (int i = 0; i < 16; ++i) Sp[(fb + i) * HDM + d] = acc[i];
    if (threadIdx.x < 64) {
        const int f = threadIdx.x;
        float s = 0.f;
        for (int l = 0; l < CT; ++l) s += fkh[l * FDM + f];
        Ks[(h * NCH + c) * FDM + f] = s;
    }
}

// ---------------------------------------------------------------------------
// Exclusive prefix over chunks (in-place). grid NH, block 256.
// ---------------------------------------------------------------------------
__global__ __launch_bounds__(256) void prefix_scan(float* __restrict__ S,
                                                   float* __restrict__ Ks) {
    const int h = blockIdx.x, t = threadIdx.x;
    float run[16] = {};
    for (int c = 0; c < NCH; ++c) {
        float* Sp = S + (h * NCH + c) * FDM * HDM;
#pragma unroll
        for (int i = 0; i < 16; ++i) {
            const int e = i * 256 + t;
            float cur = Sp[e];
            Sp[e] = run[i];
            run[i] += cur;
        }
    }
    if (t < 64) {
        float rk = 0.f;
        for (int c = 0; c < NCH; ++c) {
            float* kp = Ks + (h * NCH + c) * FDM + t;
            float cur = *kp; *kp = rk; rk += cur;
        }
    }
}

// ---------------------------------------------------------------------------
// Intra-chunk attention + prefix-state apply.
// y[l,d] = sum_f fq[l,f]*S_pre[f,d] + sum_{l'<=l} (fq[l]·fk[l']) v[l',d]
// den[l] = sum_f fq[l,f]*Ks_pre[f] + sum_{l'<=l} (fq[l]·fk[l']) + EPS
// out Y[l0+l, h*64+d] = y/den.   grid (NCH, NH), block 256.
// thread: l = lane, wave w handles 16 columns (l'-block for P, d-block for y).
// ---------------------------------------------------------------------------
__global__ __launch_bounds__(256) void intra_attn(const float* __restrict__ fq,
                                                  const float* __restrict__ fk,
                                                  const float* __restrict__ V,
                                                  const float* __restrict__ S,
                                                  const float* __restrict__ Ks,
                                                  float* __restrict__ Y) {
    __shared__ float fqs[CT][FDM + 1];  // padded: read at fixed f, varying l
    __shared__ float vs[CT][HDM];       // read wave-uniform -> broadcast
    __shared__ float PT[CT][CT];        // P transposed: PT[l'][l]
    const int c = blockIdx.x, h = blockIdx.y;
    const int t = threadIdx.x;
    const int l = t & 63, w = (t >> 6) * 16;
    const int l0 = c * CT;

    for (int i = 0; i < 16; ++i) {
        const int e = i * 256 + t;
        const int r = e >> 6, cc = e & 63;
        fqs[r][cc] = fq[(h * LQ + l0 + r) * FDM + cc];
        vs[r][cc]  = V[(l0 + r) * HID + h * HDM + cc];
    }
    __syncthreads();

    // scores: P[l][l'] for l' in [w, w+16)
    float accp[16] = {};
    const float* fkb = fk + (h * LQ + l0) * FDM;
    for (int f = 0; f < FDM; ++f) {
        const float a = fqs[l][f];
#pragma unroll
        for (int j = 0; j < 16; ++j)
            accp[j] += a * fkb[(w + j) * FDM + f];   // wave-uniform read
    }
#pragma unroll
    for (int j = 0; j < 16; ++j) PT[w + j][l] = accp[j];
    __syncthreads();

    // output: prefix-state part + masked intra part
    const float* Sp = S + (h * NCH + c) * FDM * HDM;   // exclusive prefix [f][d]
    const float* kp = Ks + (h * NCH + c) * FDM;
    float y[16] = {};
    float den = EPSV;
    for (int f = 0; f < FDM; ++f) {
        const float a = fqs[l][f];
        den += a * kp[f];
        const float* sr = Sp + f * HDM + w;
#pragma unroll
        for (int i = 0; i < 16; ++i) y[i] += a * sr[i];
    }
    for (int lp = 0; lp < CT; ++lp) {
        const float p = (lp <= l) ? PT[lp][l] : 0.f;
        den += p;
#pragma unroll
        for (int i = 0; i < 16; ++i) y[i] += p * vs[lp][w + i];
    }
    const float inv = 1.0f / den;
    float* yo = Y + (l0 + l) * HID + h * HDM + w;
#pragma unroll
    for (int i = 0; i < 16; i += 4) {
        float4 o = make_float4(y[i] * inv, y[i + 1] * inv, y[i + 2] * inv, y[i + 3] * inv);
        *(float4*)&yo[i] = o;
    }
}

// ---------------------------------------------------------------------------
extern "C" void kernel_launch(void* const* d_in, const int* in_sizes, int n_in,
                              void* d_out, int out_size, void* d_ws, size_t ws_size,
                              hipStream_t stream) {
    const float* hs  = (const float*)d_in[0];
    const float* Wq  = (const float*)d_in[1];
    const float* Wk  = (const float*)d_in[2];
    const float* Wv  = (const float*)d_in[3];
    const float* Wo  = (const float*)d_in[4];
    const float* Wfq = (const float*)d_in[5];
    const float* Wfk = (const float*)d_in[6];
    float* out = (float*)d_out;

    float* ws = (float*)d_ws;
    const size_t SZ = (size_t)LQ * HID;          // 2,097,152 floats
    float* q   = ws;
    float* k   = ws + SZ;
    float* v   = ws + 2 * SZ;
    float* fqb = ws + 3 * SZ;                    // [h][l][f]
    float* fkb = ws + 4 * SZ;                    // [h][l][f]
    float* S   = ws + 5 * SZ;                    // [h][c][f][d]
    float* Ks  = ws + 6 * SZ;                    // [h][c][f]
    float* y   = q;                              // reuse q (consumed by feature_map)

    dim3 gg(HID / 64, LQ / 64);
    gemm_nt<<<gg, 256, 0, stream>>>(hs, Wq, q, LQ, HID, HID);
    gemm_nt<<<gg, 256, 0, stream>>>(hs, Wk, k, LQ, HID, HID);
    gemm_nt<<<gg, 256, 0, stream>>>(hs, Wv, v, LQ, HID, HID);

    feature_map<<<dim3(LQ, NH), 64, 0, stream>>>(q, Wfq, fqb);
    feature_map<<<dim3(LQ, NH), 64, 0, stream>>>(k, Wfk, fkb);

    chunk_sums<<<dim3(NCH, NH), 256, 0, stream>>>(fkb, v, S, Ks);
    prefix_scan<<<NH, 256, 0, stream>>>(S, Ks);
    intra_attn<<<dim3(NCH, NH), 256, 0, stream>>>(fqb, fkb, v, S, Ks, y);

    gemm_nt<<<gg, 256, 0, stream>>>(y, Wo, out, LQ, HID, HID);
}

// Round 2
// 334.428 us; speedup vs baseline: 2.6086x; 2.6086x over previous
//
#include <hip/hip_runtime.h>
#include <math.h>

// Problem constants
constexpr int LQ  = 1024;   // sequence length
constexpr int NH  = 32;     // heads
constexpr int HDM = 64;     // head dim
constexpr int FDM = 64;     // feature dim
constexpr int HID = 2048;   // NH*HDM
constexpr int NCH = 16;     // chunks
constexpr int CT  = 64;     // chunk length (NCH*CT == LQ)
#define EPSV 1e-12f

typedef __bf16 bf16x8 __attribute__((ext_vector_type(8)));
typedef float  f32x4  __attribute__((ext_vector_type(4)));

// fp32 -> bf16 raw bits, round-to-nearest-even
__device__ __forceinline__ unsigned short f2b_raw(float x) {
    union { float f; unsigned int u; } v; v.f = x;
    unsigned int r = v.u + 0x7fffu + ((v.u >> 16) & 1u);
    return (unsigned short)(r >> 16);
}

// async global->LDS, 16B per lane; lds dst = wave-uniform base + lane*16
#define ASYNC16(ldsp, gp) __builtin_amdgcn_global_load_lds( \
    (const __attribute__((address_space(1))) void*)(gp),    \
    (__attribute__((address_space(3))) void*)(ldsp), 16, 0, 0)

// ---------------------------------------------------------------------------
// bf16 MFMA GEMM (NT): C[M,N] = A[M,K] * B[N,K]^T. A,B bf16 raw (ushort),
// C fp32. 128x128 tile, BK=32, 256 threads = 4 waves, each wave 64x64
// (4x4 grid of 16x16x32 MFMAs). m97 structure: global_load_lds width 16,
// contiguous [row][32] bf16 LDS tiles, ds_read_b128 fragments.
// ---------------------------------------------------------------------------
__device__ __forceinline__ void gemm_body(const ushort* __restrict__ A,
                                          const ushort* __restrict__ B,
                                          float* __restrict__ C,
                                          int M, int N, int K) {
    __shared__ __align__(16) ushort As[128 * 32];
    __shared__ __align__(16) ushort Bs[128 * 32];
    const int t    = threadIdx.x;
    const int wave = t >> 6, lane = t & 63;
    const int wm   = (wave >> 1) * 64, wn = (wave & 1) * 64;
    const int bm   = blockIdx.y * 128, bn = blockIdx.x * 128;

    // staging: each wave loads 2x16 rows of A and 2x16 rows of B (16B/lane)
    const int lrow = lane >> 2;          // 0..15
    const int lk   = (lane & 3) * 8;     // element offset within BK
    const ushort* ga0 = A + (size_t)(bm + wave * 32 + lrow) * K + lk;
    const ushort* ga1 = ga0 + 16 * (size_t)K;
    const ushort* gb0 = B + (size_t)(bn + wave * 32 + lrow) * K + lk;
    const ushort* gb1 = gb0 + 16 * (size_t)K;
    ushort* la0 = As + (wave * 32) * 32;   // wave-uniform LDS bases
    ushort* la1 = la0 + 16 * 32;
    ushort* lb0 = Bs + (wave * 32) * 32;
    ushort* lb1 = lb0 + 16 * 32;

    const int fr = lane & 15;            // fragment row
    const int fo = (lane >> 4) * 8;      // fragment k-offset (elements)

    f32x4 acc[4][4] = {};

    for (int k0 = 0; k0 < K; k0 += 32) {
        __syncthreads();                 // previous compute done before overwrite
        ASYNC16(la0, ga0); ASYNC16(la1, ga1);
        ASYNC16(lb0, gb0); ASYNC16(lb1, gb1);
        ga0 += 32; ga1 += 32; gb0 += 32; gb1 += 32;
        __syncthreads();                 // vmcnt(0) drain: loads visible
        bf16x8 af[4], bg[4];
#pragma unroll
        for (int i = 0; i < 4; ++i) af[i] = *(const bf16x8*)&As[(wm + i * 16 + fr) * 32 + fo];
#pragma unroll
        for (int j = 0; j < 4; ++j) bg[j] = *(const bf16x8*)&Bs[(wn + j * 16 + fr) * 32 + fo];
#pragma unroll
        for (int i = 0; i < 4; ++i)
#pragma unroll
            for (int j = 0; j < 4; ++j)
                acc[i][j] = __builtin_amdgcn_mfma_f32_16x16x32_bf16(af[i], bg[j], acc[i][j], 0, 0, 0);
    }

    // epilogue: C/D layout col=lane&15, row=(lane>>4)*4+reg
    const int er = (lane >> 4) * 4;
    const int ec = lane & 15;
#pragma unroll
    for (int i = 0; i < 4; ++i)
#pragma unroll
        for (int j = 0; j < 4; ++j) {
            float* cp = C + (size_t)(bm + wm + i * 16 + er) * N + bn + wn + j * 16 + ec;
#pragma unroll
            for (int r = 0; r < 4; ++r) cp[(size_t)r * N] = acc[i][j][r];
        }
}

__global__ __launch_bounds__(256) void gemm_qkv(const ushort* __restrict__ hsb,
                                                const ushort* __restrict__ wqb,
                                                const ushort* __restrict__ wkb,
                                                const ushort* __restrict__ wvb,
                                                float* __restrict__ q,
                                                float* __restrict__ k,
                                                float* __restrict__ v) {
    const ushort* B; float* C;
    if (blockIdx.z == 0)      { B = wqb; C = q; }
    else if (blockIdx.z == 1) { B = wkb; C = k; }
    else                      { B = wvb; C = v; }
    gemm_body(hsb, B, C, LQ, HID, HID);
}

__global__ __launch_bounds__(256) void gemm_one(const ushort* __restrict__ A,
                                                const ushort* __restrict__ B,
                                                float* __restrict__ C) {
    gemm_body(A, B, C, LQ, HID, HID);
}

// ---------------------------------------------------------------------------
// fp32 -> bf16 conversion, 5 tensors in one dispatch (grid.y selects tensor)
// ---------------------------------------------------------------------------
struct F2BArgs { const float* src[5]; ushort* dst[5]; int n[5]; };
__global__ __launch_bounds__(256) void f2b_multi(F2BArgs p) {
    const int which = blockIdx.y;
    const float* s = p.src[which];
    ushort* d = p.dst[which];
    const int n = p.n[which];
    const int i = (blockIdx.x * 256 + threadIdx.x) * 4;
    if (i >= n) return;
    float4 v = *(const float4*)&s[i];
    ushort4 o = make_ushort4(f2b_raw(v.x), f2b_raw(v.y), f2b_raw(v.z), f2b_raw(v.w));
    *(ushort4*)&d[i] = o;
}

// ---------------------------------------------------------------------------
// Feature map: z[f] = sum_d X[l, h*64+d] * Wf[h, d, f]; softmax over f (64).
// grid (LQ, NH), block 64. Output layout [h][l][f].
// ---------------------------------------------------------------------------
__global__ __launch_bounds__(64) void feature_map(const float* __restrict__ X,
                                                  const float* __restrict__ Wf,
                                                  float* __restrict__ out) {
    const int l = blockIdx.x, h = blockIdx.y, f = threadIdx.x;
    __shared__ float xs[64];
    xs[f] = X[l * HID + h * HDM + f];
    __syncthreads();
    float z = 0.f;
    const float* w = Wf + h * HDM * FDM + f;
#pragma unroll 8
    for (int d = 0; d < HDM; ++d) z += xs[d] * w[d * FDM];
    float m = z;
#pragma unroll
    for (int off = 32; off; off >>= 1) m = fmaxf(m, __shfl_xor(m, off));
    float e = __expf(z - m);
    float s = e;
#pragma unroll
    for (int off = 32; off; off >>= 1) s += __shfl_xor(s, off);
    out[(h * LQ + l) * FDM + f] = e / s;
}

// ---------------------------------------------------------------------------
// Per-chunk inclusive sums: S_c[f][d] = sum_{l in chunk} fk[l,f]*v[l,d],
// Ks_c[f] = sum_{l in chunk} fk[l,f].  grid (NCH, NH), block 256.
// ---------------------------------------------------------------------------
__global__ __launch_bounds__(256) void chunk_sums(const float* __restrict__ fk,
                                                  const float* __restrict__ V,
                                                  float* __restrict__ S,
                                                  float* __restrict__ Ks) {
    const int c = blockIdx.x, h = blockIdx.y;
    const int d = threadIdx.x & 63, fb = (threadIdx.x >> 6) * 16;
    const int l0 = c * CT;
    const float* fkh = fk + (h * LQ + l0) * FDM;
    const float* vh  = V + l0 * HID + h * HDM;
    float acc[16] = {};
    for (int l = 0; l < CT; ++l) {
        float vv = vh[l * HID + d];
        const float* fr = fkh + l * FDM + fb;
#pragma unroll
        for (int i = 0; i < 16; ++i) acc[i] += fr[i] * vv;
    }
    float* Sp = S + (h * NCH + c) * FDM * HDM;
#pragma unroll
    for (int i = 0; i < 16; ++i) Sp[(fb + i) * HDM + d] = acc[i];
    if (threadIdx.x < 64) {
        const int f = threadIdx.x;
        float s = 0.f;
        for (int l = 0; l < CT; ++l) s += fkh[l * FDM + f];
        Ks[(h * NCH + c) * FDM + f] = s;
    }
}

// ---------------------------------------------------------------------------
// Exclusive prefix over chunks (in-place). grid NH, block 256.
// ---------------------------------------------------------------------------
__global__ __launch_bounds__(256) void prefix_scan(float* __restrict__ S,
                                                   float* __restrict__ Ks) {
    const int h = blockIdx.x, t = threadIdx.x;
    float run[16] = {};
    for (int c = 0; c < NCH; ++c) {
        float* Sp = S + (h * NCH + c) * FDM * HDM;
#pragma unroll
        for (int i = 0; i < 16; ++i) {
            const int e = i * 256 + t;
            float cur = Sp[e];
            Sp[e] = run[i];
            run[i] += cur;
        }
    }
    if (t < 64) {
        float rk = 0.f;
        for (int c = 0; c < NCH; ++c) {
            float* kp = Ks + (h * NCH + c) * FDM + t;
            float cur = *kp; *kp = rk; rk += cur;
        }
    }
}

// ---------------------------------------------------------------------------
// Intra-chunk attention + prefix-state apply; writes bf16 output for the
// final projection GEMM.  grid (NCH, NH), block 256.
// ---------------------------------------------------------------------------
__global__ __launch_bounds__(256) void intra_attn(const float* __restrict__ fq,
                                                  const float* __restrict__ fk,
                                                  const float* __restrict__ V,
                                                  const float* __restrict__ S,
                                                  const float* __restrict__ Ks,
                                                  ushort* __restrict__ Yb) {
    __shared__ float fqs[CT][FDM + 1];  // padded: read at fixed f, varying l
    __shared__ float vs[CT][HDM];       // read wave-uniform -> broadcast
    __shared__ float PT[CT][CT];        // P transposed: PT[l'][l]
    const int c = blockIdx.x, h = blockIdx.y;
    const int t = threadIdx.x;
    const int l = t & 63, w = (t >> 6) * 16;
    const int l0 = c * CT;

    for (int i = 0; i < 16; ++i) {
        const int e = i * 256 + t;
        const int r = e >> 6, cc = e & 63;
        fqs[r][cc] = fq[(h * LQ + l0 + r) * FDM + cc];
        vs[r][cc]  = V[(l0 + r) * HID + h * HDM + cc];
    }
    __syncthreads();

    // scores: P[l][l'] for l' in [w, w+16)
    float accp[16] = {};
    const float* fkb = fk + (h * LQ + l0) * FDM;
    for (int f = 0; f < FDM; ++f) {
        const float a = fqs[l][f];
#pragma unroll
        for (int j = 0; j < 16; ++j)
            accp[j] += a * fkb[(w + j) * FDM + f];   // wave-uniform read
    }
#pragma unroll
    for (int j = 0; j < 16; ++j) PT[w + j][l] = accp[j];
    __syncthreads();

    // output: prefix-state part + masked intra part
    const float* Sp = S + (h * NCH + c) * FDM * HDM;   // exclusive prefix [f][d]
    const float* kp = Ks + (h * NCH + c) * FDM;
    float y[16] = {};
    float den = EPSV;
    for (int f = 0; f < FDM; ++f) {
        const float a = fqs[l][f];
        den += a * kp[f];
        const float* sr = Sp + f * HDM + w;
#pragma unroll
        for (int i = 0; i < 16; ++i) y[i] += a * sr[i];
    }
    for (int lp = 0; lp < CT; ++lp) {
        const float p = (lp <= l) ? PT[lp][l] : 0.f;
        den += p;
#pragma unroll
        for (int i = 0; i < 16; ++i) y[i] += p * vs[lp][w + i];
    }
    const float inv = 1.0f / den;
    ushort* yo = Yb + (size_t)(l0 + l) * HID + h * HDM + w;
#pragma unroll
    for (int i = 0; i < 16; i += 4) {
        ushort4 o = make_ushort4(f2b_raw(y[i] * inv), f2b_raw(y[i + 1] * inv),
                                 f2b_raw(y[i + 2] * inv), f2b_raw(y[i + 3] * inv));
        *(ushort4*)&yo[i] = o;
    }
}

// ---------------------------------------------------------------------------
extern "C" void kernel_launch(void* const* d_in, const int* in_sizes, int n_in,
                              void* d_out, int out_size, void* d_ws, size_t ws_size,
                              hipStream_t stream) {
    const float* hs  = (const float*)d_in[0];
    const float* Wq  = (const float*)d_in[1];
    const float* Wk  = (const float*)d_in[2];
    const float* Wv  = (const float*)d_in[3];
    const float* Wo  = (const float*)d_in[4];
    const float* Wfq = (const float*)d_in[5];
    const float* Wfk = (const float*)d_in[6];
    float* out = (float*)d_out;

    float* ws = (float*)d_ws;
    const size_t SZ = (size_t)LQ * HID;          // 2,097,152
    const size_t WZ = (size_t)HID * HID;         // 4,194,304
    float* q   = ws;
    float* k   = ws + SZ;
    float* v   = ws + 2 * SZ;
    float* fqb = ws + 3 * SZ;                    // [h][l][f]
    float* fkb = ws + 4 * SZ;                    // [h][l][f]
    float* S   = ws + 5 * SZ;                    // [h][c][f][d]
    float* Ks  = ws + 6 * SZ;                    // [h][c][f]
    ushort* hsb = (ushort*)(Ks + 32768);
    ushort* wqb = hsb + SZ;
    ushort* wkb = wqb + WZ;
    ushort* wvb = wkb + WZ;
    ushort* wob = wvb + WZ;
    ushort* yb  = wob + WZ;

    F2BArgs fa;
    fa.src[0] = hs; fa.dst[0] = hsb; fa.n[0] = (int)SZ;
    fa.src[1] = Wq; fa.dst[1] = wqb; fa.n[1] = (int)WZ;
    fa.src[2] = Wk; fa.dst[2] = wkb; fa.n[2] = (int)WZ;
    fa.src[3] = Wv; fa.dst[3] = wvb; fa.n[3] = (int)WZ;
    fa.src[4] = Wo; fa.dst[4] = wob; fa.n[4] = (int)WZ;
    f2b_multi<<<dim3((unsigned)(WZ / 1024), 5), 256, 0, stream>>>(fa);

    gemm_qkv<<<dim3(HID / 128, LQ / 128, 3), 256, 0, stream>>>(hsb, wqb, wkb, wvb, q, k, v);

    feature_map<<<dim3(LQ, NH), 64, 0, stream>>>(q, Wfq, fqb);
    feature_map<<<dim3(LQ, NH), 64, 0, stream>>>(k, Wfk, fkb);

    chunk_sums<<<dim3(NCH, NH), 256, 0, stream>>>(fkb, v, S, Ks);
    prefix_scan<<<NH, 256, 0, stream>>>(S, Ks);
    intra_attn<<<dim3(NCH, NH), 256, 0, stream>>>(fqb, fkb, v, S, Ks, yb);

    gemm_one<<<dim3(HID / 128, LQ / 128), 256, 0, stream>>>(yb, wob, out);
}

// Round 3
// 226.415 us; speedup vs baseline: 3.8530x; 1.4771x over previous
//
#include <hip/hip_runtime.h>
#include <math.h>

// Problem constants
constexpr int LQ  = 1024;   // sequence length
constexpr int NH  = 32;     // heads
constexpr int HDM = 64;     // head dim
constexpr int FDM = 64;     // feature dim
constexpr int HID = 2048;   // NH*HDM
constexpr int NCH = 16;     // chunks
constexpr int CT  = 64;     // chunk length (NCH*CT == LQ)
#define EPSV 1e-12f

typedef __bf16 bf16x8 __attribute__((ext_vector_type(8)));
typedef float  f32x4  __attribute__((ext_vector_type(4)));

// fp32 -> bf16 raw bits, round-to-nearest-even
__device__ __forceinline__ unsigned short f2b_raw(float x) {
    union { float f; unsigned int u; } v; v.f = x;
    unsigned int r = v.u + 0x7fffu + ((v.u >> 16) & 1u);
    return (unsigned short)(r >> 16);
}
__device__ __forceinline__ float b2f(ushort u) {
    union { unsigned int i; float f; } v; v.i = ((unsigned int)u) << 16; return v.f;
}

// async global->LDS, 16B per lane; lds dst = wave-uniform base + lane*16
#define ASYNC16(ldsp, gp) __builtin_amdgcn_global_load_lds( \
    (const __attribute__((address_space(1))) void*)(gp),    \
    (__attribute__((address_space(3))) void*)(ldsp), 16, 0, 0)

// ---------------------------------------------------------------------------
// bf16 MFMA GEMM (NT): C[M,N] = A[M,K] * B[N,K]^T. A,B bf16 raw (ushort).
// 128x128 tile, BK=32, 256 threads = 4 waves, each wave 64x64.
// BF16OUT: write bf16 (ushort) output, else fp32.
// ---------------------------------------------------------------------------
template <bool BF16OUT>
__device__ __forceinline__ void gemm_body(const ushort* __restrict__ A,
                                          const ushort* __restrict__ B,
                                          void* __restrict__ Cv,
                                          int M, int N, int K) {
    __shared__ __align__(16) ushort As[128 * 32];
    __shared__ __align__(16) ushort Bs[128 * 32];
    const int t    = threadIdx.x;
    const int wave = t >> 6, lane = t & 63;
    const int wm   = (wave >> 1) * 64, wn = (wave & 1) * 64;
    const int bm   = blockIdx.y * 128, bn = blockIdx.x * 128;

    const int lrow = lane >> 2;
    const int lk   = (lane & 3) * 8;
    const ushort* ga0 = A + (size_t)(bm + wave * 32 + lrow) * K + lk;
    const ushort* ga1 = ga0 + 16 * (size_t)K;
    const ushort* gb0 = B + (size_t)(bn + wave * 32 + lrow) * K + lk;
    const ushort* gb1 = gb0 + 16 * (size_t)K;
    ushort* la0 = As + (wave * 32) * 32;
    ushort* la1 = la0 + 16 * 32;
    ushort* lb0 = Bs + (wave * 32) * 32;
    ushort* lb1 = lb0 + 16 * 32;

    const int fr = lane & 15;
    const int fo = (lane >> 4) * 8;

    f32x4 acc[4][4] = {};

    for (int k0 = 0; k0 < K; k0 += 32) {
        __syncthreads();
        ASYNC16(la0, ga0); ASYNC16(la1, ga1);
        ASYNC16(lb0, gb0); ASYNC16(lb1, gb1);
        ga0 += 32; ga1 += 32; gb0 += 32; gb1 += 32;
        __syncthreads();
        bf16x8 af[4], bg[4];
#pragma unroll
        for (int i = 0; i < 4; ++i) af[i] = *(const bf16x8*)&As[(wm + i * 16 + fr) * 32 + fo];
#pragma unroll
        for (int j = 0; j < 4; ++j) bg[j] = *(const bf16x8*)&Bs[(wn + j * 16 + fr) * 32 + fo];
#pragma unroll
        for (int i = 0; i < 4; ++i)
#pragma unroll
            for (int j = 0; j < 4; ++j)
                acc[i][j] = __builtin_amdgcn_mfma_f32_16x16x32_bf16(af[i], bg[j], acc[i][j], 0, 0, 0);
    }

    const int er = (lane >> 4) * 4;
    const int ec = lane & 15;
#pragma unroll
    for (int i = 0; i < 4; ++i)
#pragma unroll
        for (int j = 0; j < 4; ++j) {
            const size_t base = (size_t)(bm + wm + i * 16 + er) * N + bn + wn + j * 16 + ec;
            if constexpr (BF16OUT) {
                ushort* C = (ushort*)Cv;
#pragma unroll
                for (int r = 0; r < 4; ++r) C[base + (size_t)r * N] = f2b_raw(acc[i][j][r]);
            } else {
                float* C = (float*)Cv;
#pragma unroll
                for (int r = 0; r < 4; ++r) C[base + (size_t)r * N] = acc[i][j][r];
            }
        }
}

__global__ __launch_bounds__(256) void gemm_qkv(const ushort* __restrict__ hsb,
                                                const ushort* __restrict__ wqb,
                                                const ushort* __restrict__ wkb,
                                                const ushort* __restrict__ wvb,
                                                ushort* __restrict__ qb,
                                                ushort* __restrict__ kb,
                                                ushort* __restrict__ vb) {
    const ushort* B; ushort* C;
    if (blockIdx.z == 0)      { B = wqb; C = qb; }
    else if (blockIdx.z == 1) { B = wkb; C = kb; }
    else                      { B = wvb; C = vb; }
    gemm_body<true>(hsb, B, C, LQ, HID, HID);
}

__global__ __launch_bounds__(256) void gemm_one(const ushort* __restrict__ A,
                                                const ushort* __restrict__ B,
                                                float* __restrict__ C) {
    gemm_body<false>(A, B, C, LQ, HID, HID);
}

// ---------------------------------------------------------------------------
// fp32 -> bf16 conversion, 5 tensors in one dispatch
// ---------------------------------------------------------------------------
struct F2BArgs { const float* src[5]; ushort* dst[5]; int n[5]; };
__global__ __launch_bounds__(256) void f2b_multi(F2BArgs p) {
    const int which = blockIdx.y;
    const float* s = p.src[which];
    ushort* d = p.dst[which];
    const int n = p.n[which];
    const int i = (blockIdx.x * 256 + threadIdx.x) * 4;
    if (i >= n) return;
    float4 v = *(const float4*)&s[i];
    ushort4 o = make_ushort4(f2b_raw(v.x), f2b_raw(v.y), f2b_raw(v.z), f2b_raw(v.w));
    *(ushort4*)&d[i] = o;
}

// ---------------------------------------------------------------------------
// Wf [h][d][f] fp32  ->  WfT [h][f][d] bf16.  grid (NH, 2), block 256.
// ---------------------------------------------------------------------------
__global__ __launch_bounds__(256) void wf_transpose(const float* __restrict__ Wfq,
                                                    const float* __restrict__ Wfk,
                                                    ushort* __restrict__ WfqT,
                                                    ushort* __restrict__ WfkT) {
    const int h = blockIdx.x, isK = blockIdx.y;
    const float* src = (isK ? Wfk : Wfq) + (size_t)h * 4096;   // [d][f]
    ushort* dst = (isK ? WfkT : WfqT) + (size_t)h * 4096;      // [f][d]
    __shared__ float tile[64][65];
    const int t = threadIdx.x;
    for (int it = 0; it < 16; ++it) {
        int e = it * 256 + t; int d = e >> 6, f = e & 63;
        tile[d][f] = src[e];
    }
    __syncthreads();
    for (int it = 0; it < 16; ++it) {
        int e = it * 256 + t; int f = e >> 6, d = e & 63;
        dst[e] = f2b_raw(tile[d][f]);
    }
}

// ---------------------------------------------------------------------------
// Feature map per (chunk, head, q|k) via MFMA + fused chunk-state (k branch).
//   Z[l][f] = X[l][:] . WfT[f][:]  (NT mfma, K=64)
//   featmap = softmax_f(Z)  -> fqB/fkB [h][l][f] bf16
// k branch additionally:
//   Fs = fk^T [f][l];  Ks_c[f] = sum_l fk[l][f]
//   Vs = V^T [d][l] -> VTb global [h][c][d][l] bf16
//   St_c[d][f] = sum_l VT[d][l]*fkT[f][l]  (NT mfma) -> Sraw fp32 [h][c][d][f]
// ---------------------------------------------------------------------------
__global__ __launch_bounds__(256) void featmap_chunk(
    const ushort* __restrict__ qb, const ushort* __restrict__ kb,
    const ushort* __restrict__ vb,
    const ushort* __restrict__ WfqT, const ushort* __restrict__ WfkT,
    ushort* __restrict__ fqB, ushort* __restrict__ fkB,
    ushort* __restrict__ VTb, float* __restrict__ Sraw, float* __restrict__ Ks) {
    __shared__ __align__(16) ushort Xs[64 * 72];
    __shared__ __align__(16) ushort Ws[64 * 72];
    __shared__ float Zs[64][68];
    __shared__ __align__(16) ushort Fs[64 * 72];
    __shared__ __align__(16) ushort Vs[64 * 72];

    const int c = blockIdx.x, h = blockIdx.y, isK = blockIdx.z;
    const int t = threadIdx.x, lane = t & 63, wave = t >> 6;
    const int l0 = c * CT;
    const int fr = lane & 15, fo = (lane >> 4) * 8;
    const int g = lane >> 4, cc = lane & 15;

    const ushort* X  = (isK ? kb : qb);
    const ushort* WT = (isK ? WfkT : WfqT) + (size_t)h * 4096;

    for (int it = 0; it < 2; ++it) {
        int e = (it * 256 + t) * 8;
        int row = e >> 6, col = e & 63;
        *(uint4*)&Xs[row * 72 + col] = *(const uint4*)&X[(size_t)(l0 + row) * HID + h * HDM + col];
        *(uint4*)&Ws[row * 72 + col] = *(const uint4*)&WT[e];
        if (isK) {
            uint4 vv = *(const uint4*)&vb[(size_t)(l0 + row) * HID + h * HDM + col];
            const ushort* pv = (const ushort*)&vv;
#pragma unroll
            for (int i = 0; i < 8; ++i) Vs[(col + i) * 72 + row] = pv[i];
        }
    }
    __syncthreads();

    // Z = X @ WT^T
    f32x4 accZ[4] = {};
#pragma unroll
    for (int kp = 0; kp < 2; ++kp) {
        bf16x8 a = *(const bf16x8*)&Xs[(wave * 16 + fr) * 72 + kp * 32 + fo];
#pragma unroll
        for (int j = 0; j < 4; ++j) {
            bf16x8 b = *(const bf16x8*)&Ws[(j * 16 + fr) * 72 + kp * 32 + fo];
            accZ[j] = __builtin_amdgcn_mfma_f32_16x16x32_bf16(a, b, accZ[j], 0, 0, 0);
        }
    }
#pragma unroll
    for (int j = 0; j < 4; ++j)
#pragma unroll
        for (int r = 0; r < 4; ++r)
            Zs[wave * 16 + g * 4 + r][j * 16 + cc] = accZ[j][r];
    __syncthreads();

    // softmax over f (64) per row; 4 threads/row
    const int srow = t >> 2, spart = t & 3;
    float zv[16], m = -1e30f;
#pragma unroll
    for (int i = 0; i < 16; ++i) { zv[i] = Zs[srow][spart * 16 + i]; m = fmaxf(m, zv[i]); }
    m = fmaxf(m, __shfl_xor(m, 1)); m = fmaxf(m, __shfl_xor(m, 2));
    float s = 0.f;
#pragma unroll
    for (int i = 0; i < 16; ++i) { zv[i] = __expf(zv[i] - m); s += zv[i]; }
    s += __shfl_xor(s, 1); s += __shfl_xor(s, 2);
    const float inv = 1.0f / s;
    ushort ov[16];
#pragma unroll
    for (int i = 0; i < 16; ++i) ov[i] = f2b_raw(zv[i] * inv);
    ushort* outp = (isK ? fkB : fqB) + ((size_t)h * LQ + l0 + srow) * FDM + spart * 16;
    *(uint4*)&outp[0] = *(uint4*)&ov[0];
    *(uint4*)&outp[8] = *(uint4*)&ov[8];
    if (isK) {
#pragma unroll
        for (int i = 0; i < 16; ++i) Fs[(spart * 16 + i) * 72 + srow] = ov[i];
    }
    if (!isK) return;
    __syncthreads();

    // Ks column sums
    if (t < 64) {
        float ks = 0.f;
#pragma unroll 8
        for (int l = 0; l < 64; ++l) ks += b2f(Fs[t * 72 + l]);
        Ks[((size_t)h * NCH + c) * FDM + t] = ks;
    }
    // VT global copy
    const size_t cb = ((size_t)h * NCH + c) * 4096;
    for (int it = 0; it < 2; ++it) {
        int e = (it * 256 + t) * 8;
        int row = e >> 6, col = e & 63;
        *(uint4*)&VTb[cb + e] = *(const uint4*)&Vs[row * 72 + col];
    }
    // St[d][f] = VT @ Fs^T
    f32x4 accS[4] = {};
#pragma unroll
    for (int kp = 0; kp < 2; ++kp) {
        bf16x8 a = *(const bf16x8*)&Vs[(wave * 16 + fr) * 72 + kp * 32 + fo];
#pragma unroll
        for (int j = 0; j < 4; ++j) {
            bf16x8 b = *(const bf16x8*)&Fs[(j * 16 + fr) * 72 + kp * 32 + fo];
            accS[j] = __builtin_amdgcn_mfma_f32_16x16x32_bf16(a, b, accS[j], 0, 0, 0);
        }
    }
    float* sp = Sraw + cb;
#pragma unroll
    for (int j = 0; j < 4; ++j)
#pragma unroll
        for (int r = 0; r < 4; ++r)
            sp[(wave * 16 + g * 4 + r) * 64 + j * 16 + cc] = accS[j][r];
}

// ---------------------------------------------------------------------------
// Exclusive prefix over chunks; state snapshot stored bf16. grid NH, block 256.
// ---------------------------------------------------------------------------
__global__ __launch_bounds__(256) void prefix2(const float* __restrict__ Sraw,
                                               ushort* __restrict__ SpreB,
                                               const float* __restrict__ Ks,
                                               float* __restrict__ Kpre) {
    const int h = blockIdx.x, t = threadIdx.x;
    float run[16] = {};
    for (int c2 = 0; c2 < NCH; ++c2) {
        const size_t base = ((size_t)h * NCH + c2) * 4096;
#pragma unroll
        for (int i = 0; i < 16; ++i) {
            int e = i * 256 + t;
            float cur = Sraw[base + e];
            SpreB[base + e] = f2b_raw(run[i]);
            run[i] += cur;
        }
    }
    if (t < 64) {
        float rk = 0.f;
        for (int c2 = 0; c2 < NCH; ++c2) {
            const size_t kb2 = ((size_t)h * NCH + c2) * FDM + t;
            float cur = Ks[kb2];
            Kpre[kb2] = rk;
            rk += cur;
        }
    }
}

// ---------------------------------------------------------------------------
// Intra-chunk attention via MFMA.
//   P = fq @ fk^T; Pm = causal-masked bf16
//   den[l] = sum fq[l]*Kpre + rowsum(Pm[l]) + EPS
//   Y[l][d] = (Pm @ V + fq @ Spre^T)[l][d] / den[l]  -> Yb bf16 [l][hid]
// ---------------------------------------------------------------------------
__global__ __launch_bounds__(256) void intra2(
    const ushort* __restrict__ fqB, const ushort* __restrict__ fkB,
    const ushort* __restrict__ VTb, const ushort* __restrict__ SpreB,
    const float* __restrict__ Kpre, ushort* __restrict__ Yb) {
    __shared__ __align__(16) ushort fqs[64 * 72];
    __shared__ __align__(16) ushort fks[64 * 72];
    __shared__ __align__(16) ushort VTs[64 * 72];
    __shared__ __align__(16) ushort Sps[64 * 72];
    __shared__ __align__(16) ushort Pms[64 * 72];
    __shared__ float den[64], kpr[64];

    const int c = blockIdx.x, h = blockIdx.y;
    const int t = threadIdx.x, lane = t & 63, wave = t >> 6;
    const int l0 = c * CT;
    const int fr = lane & 15, fo = (lane >> 4) * 8;
    const int g = lane >> 4, cc = lane & 15;

    const size_t qkbase = ((size_t)h * LQ + l0) * FDM;
    const size_t cbase  = ((size_t)h * NCH + c) * 4096;
    for (int it = 0; it < 2; ++it) {
        int e = (it * 256 + t) * 8;
        int row = e >> 6, col = e & 63;
        *(uint4*)&fqs[row * 72 + col] = *(const uint4*)&fqB[qkbase + e];
        *(uint4*)&fks[row * 72 + col] = *(const uint4*)&fkB[qkbase + e];
        *(uint4*)&VTs[row * 72 + col] = *(const uint4*)&VTb[cbase + e];
        *(uint4*)&Sps[row * 72 + col] = *(const uint4*)&SpreB[cbase + e];
    }
    if (t < 64) kpr[t] = Kpre[((size_t)h * NCH + c) * FDM + t];
    __syncthreads();

    // P = fq @ fk^T
    f32x4 accP[4] = {};
#pragma unroll
    for (int kp = 0; kp < 2; ++kp) {
        bf16x8 a = *(const bf16x8*)&fqs[(wave * 16 + fr) * 72 + kp * 32 + fo];
#pragma unroll
        for (int j = 0; j < 4; ++j) {
            bf16x8 b = *(const bf16x8*)&fks[(j * 16 + fr) * 72 + kp * 32 + fo];
            accP[j] = __builtin_amdgcn_mfma_f32_16x16x32_bf16(a, b, accP[j], 0, 0, 0);
        }
    }
#pragma unroll
    for (int j = 0; j < 4; ++j)
#pragma unroll
        for (int r = 0; r < 4; ++r) {
            int l = wave * 16 + g * 4 + r, lp = j * 16 + cc;
            Pms[l * 72 + lp] = (lp <= l) ? f2b_raw(accP[j][r]) : (ushort)0;
        }
    __syncthreads();

    // denominator, 4 threads/row
    {
        const int srow = t >> 2, spart = t & 3;
        float s = 0.f;
#pragma unroll
        for (int i = 0; i < 16; ++i) s += b2f(Pms[srow * 72 + spart * 16 + i]);
#pragma unroll
        for (int i = 0; i < 16; ++i) s += b2f(fqs[srow * 72 + spart * 16 + i]) * kpr[spart * 16 + i];
        s += __shfl_xor(s, 1); s += __shfl_xor(s, 2);
        if (spart == 0) den[srow] = s + EPSV;
    }
    __syncthreads();

    // Y = Pm @ V + fq @ Spre^T
    f32x4 accY[4] = {};
#pragma unroll
    for (int kp = 0; kp < 2; ++kp) {
        bf16x8 a = *(const bf16x8*)&Pms[(wave * 16 + fr) * 72 + kp * 32 + fo];
#pragma unroll
        for (int j = 0; j < 4; ++j) {
            bf16x8 b = *(const bf16x8*)&VTs[(j * 16 + fr) * 72 + kp * 32 + fo];
            accY[j] = __builtin_amdgcn_mfma_f32_16x16x32_bf16(a, b, accY[j], 0, 0, 0);
        }
    }
#pragma unroll
    for (int kp = 0; kp < 2; ++kp) {
        bf16x8 a = *(const bf16x8*)&fqs[(wave * 16 + fr) * 72 + kp * 32 + fo];
#pragma unroll
        for (int j = 0; j < 4; ++j) {
            bf16x8 b = *(const bf16x8*)&Sps[(j * 16 + fr) * 72 + kp * 32 + fo];
            accY[j] = __builtin_amdgcn_mfma_f32_16x16x32_bf16(a, b, accY[j], 0, 0, 0);
        }
    }
#pragma unroll
    for (int r = 0; r < 4; ++r) {
        int l = wave * 16 + g * 4 + r;
        float inv = 1.0f / den[l];
        ushort* yo = Yb + (size_t)(l0 + l) * HID + h * HDM;
#pragma unroll
        for (int j = 0; j < 4; ++j)
            yo[j * 16 + cc] = f2b_raw(accY[j][r] * inv);
    }
}

// ---------------------------------------------------------------------------
extern "C" void kernel_launch(void* const* d_in, const int* in_sizes, int n_in,
                              void* d_out, int out_size, void* d_ws, size_t ws_size,
                              hipStream_t stream) {
    const float* hs  = (const float*)d_in[0];
    const float* Wq  = (const float*)d_in[1];
    const float* Wk  = (const float*)d_in[2];
    const float* Wv  = (const float*)d_in[3];
    const float* Wo  = (const float*)d_in[4];
    const float* Wfq = (const float*)d_in[5];
    const float* Wfk = (const float*)d_in[6];
    float* out = (float*)d_out;

    const size_t SZ = (size_t)LQ * HID;          // 2,097,152
    const size_t WZ = (size_t)HID * HID;         // 4,194,304

    char* w = (char*)d_ws;
    auto aus = [&](size_t n) { ushort* p = (ushort*)w; w += n * sizeof(ushort); return p; };
    auto afl = [&](size_t n) { float*  p = (float*)w;  w += n * sizeof(float);  return p; };

    ushort* hsb   = aus(SZ);
    ushort* wqb   = aus(WZ);
    ushort* wkb   = aus(WZ);
    ushort* wvb   = aus(WZ);
    ushort* wob   = aus(WZ);
    ushort* qb2   = aus(SZ);
    ushort* kb2   = aus(SZ);
    ushort* vb2   = aus(SZ);
    ushort* fqB   = aus(SZ);
    ushort* fkB   = aus(SZ);
    ushort* VTb   = aus(SZ);
    ushort* WfqT  = aus((size_t)NH * 4096);
    ushort* WfkT  = aus((size_t)NH * 4096);
    ushort* SpreB = aus(SZ);
    ushort* Yb    = aus(SZ);
    float*  Sraw  = afl(SZ);
    float*  Ks    = afl((size_t)NH * NCH * FDM);
    float*  Kpre  = afl((size_t)NH * NCH * FDM);

    F2BArgs fa;
    fa.src[0] = hs; fa.dst[0] = hsb; fa.n[0] = (int)SZ;
    fa.src[1] = Wq; fa.dst[1] = wqb; fa.n[1] = (int)WZ;
    fa.src[2] = Wk; fa.dst[2] = wkb; fa.n[2] = (int)WZ;
    fa.src[3] = Wv; fa.dst[3] = wvb; fa.n[3] = (int)WZ;
    fa.src[4] = Wo; fa.dst[4] = wob; fa.n[4] = (int)WZ;
    f2b_multi<<<dim3((unsigned)(WZ / 1024), 5), 256, 0, stream>>>(fa);

    wf_transpose<<<dim3(NH, 2), 256, 0, stream>>>(Wfq, Wfk, WfqT, WfkT);

    gemm_qkv<<<dim3(HID / 128, LQ / 128, 3), 256, 0, stream>>>(hsb, wqb, wkb, wvb, qb2, kb2, vb2);

    featmap_chunk<<<dim3(NCH, NH, 2), 256, 0, stream>>>(qb2, kb2, vb2, WfqT, WfkT,
                                                        fqB, fkB, VTb, Sraw, Ks);

    prefix2<<<NH, 256, 0, stream>>>(Sraw, SpreB, Ks, Kpre);

    intra2<<<dim3(NCH, NH), 256, 0, stream>>>(fqB, fkB, VTb, SpreB, Kpre, Yb);

    gemm_one<<<dim3(HID / 128, LQ / 128), 256, 0, stream>>>(Yb, wob, out);
}

// Round 4
// 212.752 us; speedup vs baseline: 4.1004x; 1.0642x over previous
//
#include <hip/hip_runtime.h>
#include <math.h>

// Problem constants
constexpr int LQ  = 1024;   // sequence length
constexpr int NH  = 32;     // heads
constexpr int HDM = 64;     // head dim
constexpr int FDM = 64;     // feature dim
constexpr int HID = 2048;   // NH*HDM
constexpr int NCH = 16;     // chunks
constexpr int CT  = 64;     // chunk length (NCH*CT == LQ)
#define EPSV 1e-12f

typedef __bf16 bf16x8 __attribute__((ext_vector_type(8)));
typedef float  f32x4  __attribute__((ext_vector_type(4)));

// fp32 -> bf16 raw bits, round-to-nearest-even
__device__ __forceinline__ unsigned short f2b_raw(float x) {
    union { float f; unsigned int u; } v; v.f = x;
    unsigned int r = v.u + 0x7fffu + ((v.u >> 16) & 1u);
    return (unsigned short)(r >> 16);
}
__device__ __forceinline__ float b2f(ushort u) {
    union { unsigned int i; float f; } v; v.i = ((unsigned int)u) << 16; return v.f;
}

// async global->LDS, 16B per lane; lds dst = wave-uniform base + lane*16
#define ASYNC16(ldsp, gp) __builtin_amdgcn_global_load_lds( \
    (const __attribute__((address_space(1))) void*)(gp),    \
    (__attribute__((address_space(3))) void*)(ldsp), 16, 0, 0)

// ---------------------------------------------------------------------------
// bf16 MFMA GEMM (NT): C[M,N] = A[M,K] * B[N,K]^T. A,B bf16 raw (ushort).
// 64(M) x 128(N) tile, BK=32, 256 threads = 4 waves (2x2), each wave 32x64
// (2x4 grid of 16x16x32 MFMAs). 3 global_load_lds(16B) per wave per K-iter.
// Sized so QKV grid = 768 blocks = 3 blocks/CU (occupancy-driven re-tile).
// ---------------------------------------------------------------------------
template <bool BF16OUT>
__device__ __forceinline__ void gemm_body(const ushort* __restrict__ A,
                                          const ushort* __restrict__ B,
                                          void* __restrict__ Cv,
                                          int M, int N, int K) {
    __shared__ __align__(16) ushort As[64 * 32];
    __shared__ __align__(16) ushort Bs[128 * 32];
    const int t    = threadIdx.x;
    const int wave = t >> 6, lane = t & 63;
    const int wr   = (wave >> 1) * 32;   // wave row offset in tile
    const int wc   = (wave & 1) * 64;    // wave col offset in tile
    const int bm   = blockIdx.y * 64, bn = blockIdx.x * 128;

    // staging: each wave loads 16 rows of A and 32 rows of B (16B/lane)
    const int lrow = lane >> 2;          // 0..15
    const int lk   = (lane & 3) * 8;     // element offset within BK
    const ushort* ga  = A + (size_t)(bm + wave * 16 + lrow) * K + lk;
    const ushort* gb0 = B + (size_t)(bn + wave * 32 + lrow) * K + lk;
    const ushort* gb1 = gb0 + 16 * (size_t)K;
    ushort* la  = As + (wave * 16) * 32;   // wave-uniform LDS bases
    ushort* lb0 = Bs + (wave * 32) * 32;
    ushort* lb1 = lb0 + 16 * 32;

    const int fr = lane & 15;            // fragment row
    const int fo = (lane >> 4) * 8;      // fragment k-offset (elements)

    f32x4 acc[2][4] = {};

    for (int k0 = 0; k0 < K; k0 += 32) {
        __syncthreads();                 // previous compute done before overwrite
        ASYNC16(la, ga); ASYNC16(lb0, gb0); ASYNC16(lb1, gb1);
        ga += 32; gb0 += 32; gb1 += 32;
        __syncthreads();                 // loads visible
        bf16x8 af[2], bg[4];
#pragma unroll
        for (int i = 0; i < 2; ++i) af[i] = *(const bf16x8*)&As[(wr + i * 16 + fr) * 32 + fo];
#pragma unroll
        for (int j = 0; j < 4; ++j) bg[j] = *(const bf16x8*)&Bs[(wc + j * 16 + fr) * 32 + fo];
#pragma unroll
        for (int i = 0; i < 2; ++i)
#pragma unroll
            for (int j = 0; j < 4; ++j)
                acc[i][j] = __builtin_amdgcn_mfma_f32_16x16x32_bf16(af[i], bg[j], acc[i][j], 0, 0, 0);
    }

    // epilogue: C/D layout col=lane&15, row=(lane>>4)*4+reg
    const int er = (lane >> 4) * 4;
    const int ec = lane & 15;
#pragma unroll
    for (int i = 0; i < 2; ++i)
#pragma unroll
        for (int j = 0; j < 4; ++j) {
            const size_t base = (size_t)(bm + wr + i * 16 + er) * N + bn + wc + j * 16 + ec;
            if constexpr (BF16OUT) {
                ushort* C = (ushort*)Cv;
#pragma unroll
                for (int r = 0; r < 4; ++r) C[base + (size_t)r * N] = f2b_raw(acc[i][j][r]);
            } else {
                float* C = (float*)Cv;
#pragma unroll
                for (int r = 0; r < 4; ++r) C[base + (size_t)r * N] = acc[i][j][r];
            }
        }
}

__global__ __launch_bounds__(256) void gemm_qkv(const ushort* __restrict__ hsb,
                                                const ushort* __restrict__ wqb,
                                                const ushort* __restrict__ wkb,
                                                const ushort* __restrict__ wvb,
                                                ushort* __restrict__ qb,
                                                ushort* __restrict__ kb,
                                                ushort* __restrict__ vb) {
    const ushort* B; ushort* C;
    if (blockIdx.z == 0)      { B = wqb; C = qb; }
    else if (blockIdx.z == 1) { B = wkb; C = kb; }
    else                      { B = wvb; C = vb; }
    gemm_body<true>(hsb, B, C, LQ, HID, HID);
}

__global__ __launch_bounds__(256) void gemm_one(const ushort* __restrict__ A,
                                                const ushort* __restrict__ B,
                                                float* __restrict__ C) {
    gemm_body<false>(A, B, C, LQ, HID, HID);
}

// ---------------------------------------------------------------------------
// fp32 -> bf16 conversion, 5 tensors in one dispatch
// ---------------------------------------------------------------------------
struct F2BArgs { const float* src[5]; ushort* dst[5]; int n[5]; };
__global__ __launch_bounds__(256) void f2b_multi(F2BArgs p) {
    const int which = blockIdx.y;
    const float* s = p.src[which];
    ushort* d = p.dst[which];
    const int n = p.n[which];
    const int i = (blockIdx.x * 256 + threadIdx.x) * 4;
    if (i >= n) return;
    float4 v = *(const float4*)&s[i];
    ushort4 o = make_ushort4(f2b_raw(v.x), f2b_raw(v.y), f2b_raw(v.z), f2b_raw(v.w));
    *(ushort4*)&d[i] = o;
}

// ---------------------------------------------------------------------------
// Wf [h][d][f] fp32  ->  WfT [h][f][d] bf16.  grid (NH, 2), block 256.
// ---------------------------------------------------------------------------
__global__ __launch_bounds__(256) void wf_transpose(const float* __restrict__ Wfq,
                                                    const float* __restrict__ Wfk,
                                                    ushort* __restrict__ WfqT,
                                                    ushort* __restrict__ WfkT) {
    const int h = blockIdx.x, isK = blockIdx.y;
    const float* src = (isK ? Wfk : Wfq) + (size_t)h * 4096;   // [d][f]
    ushort* dst = (isK ? WfkT : WfqT) + (size_t)h * 4096;      // [f][d]
    __shared__ float tile[64][65];
    const int t = threadIdx.x;
    for (int it = 0; it < 16; ++it) {
        int e = it * 256 + t; int d = e >> 6, f = e & 63;
        tile[d][f] = src[e];
    }
    __syncthreads();
    for (int it = 0; it < 16; ++it) {
        int e = it * 256 + t; int f = e >> 6, d = e & 63;
        dst[e] = f2b_raw(tile[d][f]);
    }
}

// ---------------------------------------------------------------------------
// Feature map per (chunk, head, q|k) via MFMA + fused chunk-state (k branch).
// ---------------------------------------------------------------------------
__global__ __launch_bounds__(256) void featmap_chunk(
    const ushort* __restrict__ qb, const ushort* __restrict__ kb,
    const ushort* __restrict__ vb,
    const ushort* __restrict__ WfqT, const ushort* __restrict__ WfkT,
    ushort* __restrict__ fqB, ushort* __restrict__ fkB,
    ushort* __restrict__ VTb, float* __restrict__ Sraw, float* __restrict__ Ks) {
    __shared__ __align__(16) ushort Xs[64 * 72];
    __shared__ __align__(16) ushort Ws[64 * 72];
    __shared__ float Zs[64][68];
    __shared__ __align__(16) ushort Fs[64 * 72];
    __shared__ __align__(16) ushort Vs[64 * 72];

    const int c = blockIdx.x, h = blockIdx.y, isK = blockIdx.z;
    const int t = threadIdx.x, lane = t & 63, wave = t >> 6;
    const int l0 = c * CT;
    const int fr = lane & 15, fo = (lane >> 4) * 8;
    const int g = lane >> 4, cc = lane & 15;

    const ushort* X  = (isK ? kb : qb);
    const ushort* WT = (isK ? WfkT : WfqT) + (size_t)h * 4096;

    for (int it = 0; it < 2; ++it) {
        int e = (it * 256 + t) * 8;
        int row = e >> 6, col = e & 63;
        *(uint4*)&Xs[row * 72 + col] = *(const uint4*)&X[(size_t)(l0 + row) * HID + h * HDM + col];
        *(uint4*)&Ws[row * 72 + col] = *(const uint4*)&WT[e];
        if (isK) {
            uint4 vv = *(const uint4*)&vb[(size_t)(l0 + row) * HID + h * HDM + col];
            const ushort* pv = (const ushort*)&vv;
#pragma unroll
            for (int i = 0; i < 8; ++i) Vs[(col + i) * 72 + row] = pv[i];
        }
    }
    __syncthreads();

    // Z = X @ WT^T
    f32x4 accZ[4] = {};
#pragma unroll
    for (int kp = 0; kp < 2; ++kp) {
        bf16x8 a = *(const bf16x8*)&Xs[(wave * 16 + fr) * 72 + kp * 32 + fo];
#pragma unroll
        for (int j = 0; j < 4; ++j) {
            bf16x8 b = *(const bf16x8*)&Ws[(j * 16 + fr) * 72 + kp * 32 + fo];
            accZ[j] = __builtin_amdgcn_mfma_f32_16x16x32_bf16(a, b, accZ[j], 0, 0, 0);
        }
    }
#pragma unroll
    for (int j = 0; j < 4; ++j)
#pragma unroll
        for (int r = 0; r < 4; ++r)
            Zs[wave * 16 + g * 4 + r][j * 16 + cc] = accZ[j][r];
    __syncthreads();

    // softmax over f (64) per row; 4 threads/row
    const int srow = t >> 2, spart = t & 3;
    float zv[16], m = -1e30f;
#pragma unroll
    for (int i = 0; i < 16; ++i) { zv[i] = Zs[srow][spart * 16 + i]; m = fmaxf(m, zv[i]); }
    m = fmaxf(m, __shfl_xor(m, 1)); m = fmaxf(m, __shfl_xor(m, 2));
    float s = 0.f;
#pragma unroll
    for (int i = 0; i < 16; ++i) { zv[i] = __expf(zv[i] - m); s += zv[i]; }
    s += __shfl_xor(s, 1); s += __shfl_xor(s, 2);
    const float inv = 1.0f / s;
    ushort ov[16];
#pragma unroll
    for (int i = 0; i < 16; ++i) ov[i] = f2b_raw(zv[i] * inv);
    ushort* outp = (isK ? fkB : fqB) + ((size_t)h * LQ + l0 + srow) * FDM + spart * 16;
    *(uint4*)&outp[0] = *(uint4*)&ov[0];
    *(uint4*)&outp[8] = *(uint4*)&ov[8];
    if (isK) {
#pragma unroll
        for (int i = 0; i < 16; ++i) Fs[(spart * 16 + i) * 72 + srow] = ov[i];
    }
    if (!isK) return;
    __syncthreads();

    // Ks column sums
    if (t < 64) {
        float ks = 0.f;
#pragma unroll 8
        for (int l = 0; l < 64; ++l) ks += b2f(Fs[t * 72 + l]);
        Ks[((size_t)h * NCH + c) * FDM + t] = ks;
    }
    // VT global copy
    const size_t cb = ((size_t)h * NCH + c) * 4096;
    for (int it = 0; it < 2; ++it) {
        int e = (it * 256 + t) * 8;
        int row = e >> 6, col = e & 63;
        *(uint4*)&VTb[cb + e] = *(const uint4*)&Vs[row * 72 + col];
    }
    // St[d][f] = VT @ Fs^T
    f32x4 accS[4] = {};
#pragma unroll
    for (int kp = 0; kp < 2; ++kp) {
        bf16x8 a = *(const bf16x8*)&Vs[(wave * 16 + fr) * 72 + kp * 32 + fo];
#pragma unroll
        for (int j = 0; j < 4; ++j) {
            bf16x8 b = *(const bf16x8*)&Fs[(j * 16 + fr) * 72 + kp * 32 + fo];
            accS[j] = __builtin_amdgcn_mfma_f32_16x16x32_bf16(a, b, accS[j], 0, 0, 0);
        }
    }
    float* sp = Sraw + cb;
#pragma unroll
    for (int j = 0; j < 4; ++j)
#pragma unroll
        for (int r = 0; r < 4; ++r)
            sp[(wave * 16 + g * 4 + r) * 64 + j * 16 + cc] = accS[j][r];
}

// ---------------------------------------------------------------------------
// Exclusive prefix over chunks; parallelized: grid (NH, 8), block 256.
// Block (h, eb) scans elements [eb*512, eb*512+512) of the 4096-elem state.
// ---------------------------------------------------------------------------
__global__ __launch_bounds__(256) void prefix2(const float* __restrict__ Sraw,
                                               ushort* __restrict__ SpreB,
                                               const float* __restrict__ Ks,
                                               float* __restrict__ Kpre) {
    const int h = blockIdx.x, eb = blockIdx.y, t = threadIdx.x;
    const int e0 = eb * 512 + t * 2;
    float r0 = 0.f, r1 = 0.f;
    const size_t hb = (size_t)h * NCH * 4096;
    for (int c2 = 0; c2 < NCH; ++c2) {
        const size_t base = hb + (size_t)c2 * 4096 + e0;
        float c0 = Sraw[base], c1 = Sraw[base + 1];
        ushort2 o = make_ushort2(f2b_raw(r0), f2b_raw(r1));
        *(ushort2*)&SpreB[base] = o;
        r0 += c0; r1 += c1;
    }
    if (eb == 0 && t < 64) {
        float rk = 0.f;
        for (int c2 = 0; c2 < NCH; ++c2) {
            const size_t kb2 = ((size_t)h * NCH + c2) * FDM + t;
            float cur = Ks[kb2];
            Kpre[kb2] = rk;
            rk += cur;
        }
    }
}

// ---------------------------------------------------------------------------
// Intra-chunk attention via MFMA.
// ---------------------------------------------------------------------------
__global__ __launch_bounds__(256) void intra2(
    const ushort* __restrict__ fqB, const ushort* __restrict__ fkB,
    const ushort* __restrict__ VTb, const ushort* __restrict__ SpreB,
    const float* __restrict__ Kpre, ushort* __restrict__ Yb) {
    __shared__ __align__(16) ushort fqs[64 * 72];
    __shared__ __align__(16) ushort fks[64 * 72];
    __shared__ __align__(16) ushort VTs[64 * 72];
    __shared__ __align__(16) ushort Sps[64 * 72];
    __shared__ __align__(16) ushort Pms[64 * 72];
    __shared__ float den[64], kpr[64];

    const int c = blockIdx.x, h = blockIdx.y;
    const int t = threadIdx.x, lane = t & 63, wave = t >> 6;
    const int l0 = c * CT;
    const int fr = lane & 15, fo = (lane >> 4) * 8;
    const int g = lane >> 4, cc = lane & 15;

    const size_t qkbase = ((size_t)h * LQ + l0) * FDM;
    const size_t cbase  = ((size_t)h * NCH + c) * 4096;
    for (int it = 0; it < 2; ++it) {
        int e = (it * 256 + t) * 8;
        int row = e >> 6, col = e & 63;
        *(uint4*)&fqs[row * 72 + col] = *(const uint4*)&fqB[qkbase + e];
        *(uint4*)&fks[row * 72 + col] = *(const uint4*)&fkB[qkbase + e];
        *(uint4*)&VTs[row * 72 + col] = *(const uint4*)&VTb[cbase + e];
        *(uint4*)&Sps[row * 72 + col] = *(const uint4*)&SpreB[cbase + e];
    }
    if (t < 64) kpr[t] = Kpre[((size_t)h * NCH + c) * FDM + t];
    __syncthreads();

    // P = fq @ fk^T
    f32x4 accP[4] = {};
#pragma unroll
    for (int kp = 0; kp < 2; ++kp) {
        bf16x8 a = *(const bf16x8*)&fqs[(wave * 16 + fr) * 72 + kp * 32 + fo];
#pragma unroll
        for (int j = 0; j < 4; ++j) {
            bf16x8 b = *(const bf16x8*)&fks[(j * 16 + fr) * 72 + kp * 32 + fo];
            accP[j] = __builtin_amdgcn_mfma_f32_16x16x32_bf16(a, b, accP[j], 0, 0, 0);
        }
    }
#pragma unroll
    for (int j = 0; j < 4; ++j)
#pragma unroll
        for (int r = 0; r < 4; ++r) {
            int l = wave * 16 + g * 4 + r, lp = j * 16 + cc;
            Pms[l * 72 + lp] = (lp <= l) ? f2b_raw(accP[j][r]) : (ushort)0;
        }
    __syncthreads();

    // denominator, 4 threads/row
    {
        const int srow = t >> 2, spart = t & 3;
        float s = 0.f;
#pragma unroll
        for (int i = 0; i < 16; ++i) s += b2f(Pms[srow * 72 + spart * 16 + i]);
#pragma unroll
        for (int i = 0; i < 16; ++i) s += b2f(fqs[srow * 72 + spart * 16 + i]) * kpr[spart * 16 + i];
        s += __shfl_xor(s, 1); s += __shfl_xor(s, 2);
        if (spart == 0) den[srow] = s + EPSV;
    }
    __syncthreads();

    // Y = Pm @ V + fq @ Spre^T
    f32x4 accY[4] = {};
#pragma unroll
    for (int kp = 0; kp < 2; ++kp) {
        bf16x8 a = *(const bf16x8*)&Pms[(wave * 16 + fr) * 72 + kp * 32 + fo];
#pragma unroll
        for (int j = 0; j < 4; ++j) {
            bf16x8 b = *(const bf16x8*)&VTs[(j * 16 + fr) * 72 + kp * 32 + fo];
            accY[j] = __builtin_amdgcn_mfma_f32_16x16x32_bf16(a, b, accY[j], 0, 0, 0);
        }
    }
#pragma unroll
    for (int kp = 0; kp < 2; ++kp) {
        bf16x8 a = *(const bf16x8*)&fqs[(wave * 16 + fr) * 72 + kp * 32 + fo];
#pragma unroll
        for (int j = 0; j < 4; ++j) {
            bf16x8 b = *(const bf16x8*)&Sps[(j * 16 + fr) * 72 + kp * 32 + fo];
            accY[j] = __builtin_amdgcn_mfma_f32_16x16x32_bf16(a, b, accY[j], 0, 0, 0);
        }
    }
#pragma unroll
    for (int r = 0; r < 4; ++r) {
        int l = wave * 16 + g * 4 + r;
        float inv = 1.0f / den[l];
        ushort* yo = Yb + (size_t)(l0 + l) * HID + h * HDM;
#pragma unroll
        for (int j = 0; j < 4; ++j)
            yo[j * 16 + cc] = f2b_raw(accY[j][r] * inv);
    }
}

// ---------------------------------------------------------------------------
extern "C" void kernel_launch(void* const* d_in, const int* in_sizes, int n_in,
                              void* d_out, int out_size, void* d_ws, size_t ws_size,
                              hipStream_t stream) {
    const float* hs  = (const float*)d_in[0];
    const float* Wq  = (const float*)d_in[1];
    const float* Wk  = (const float*)d_in[2];
    const float* Wv  = (const float*)d_in[3];
    const float* Wo  = (const float*)d_in[4];
    const float* Wfq = (const float*)d_in[5];
    const float* Wfk = (const float*)d_in[6];
    float* out = (float*)d_out;

    const size_t SZ = (size_t)LQ * HID;          // 2,097,152
    const size_t WZ = (size_t)HID * HID;         // 4,194,304

    char* w = (char*)d_ws;
    auto aus = [&](size_t n) { ushort* p = (ushort*)w; w += n * sizeof(ushort); return p; };
    auto afl = [&](size_t n) { float*  p = (float*)w;  w += n * sizeof(float);  return p; };

    ushort* hsb   = aus(SZ);
    ushort* wqb   = aus(WZ);
    ushort* wkb   = aus(WZ);
    ushort* wvb   = aus(WZ);
    ushort* wob   = aus(WZ);
    ushort* qb2   = aus(SZ);
    ushort* kb2   = aus(SZ);
    ushort* vb2   = aus(SZ);
    ushort* fqB   = aus(SZ);
    ushort* fkB   = aus(SZ);
    ushort* VTb   = aus(SZ);
    ushort* WfqT  = aus((size_t)NH * 4096);
    ushort* WfkT  = aus((size_t)NH * 4096);
    ushort* SpreB = aus(SZ);
    ushort* Yb    = aus(SZ);
    float*  Sraw  = afl(SZ);
    float*  Ks    = afl((size_t)NH * NCH * FDM);
    float*  Kpre  = afl((size_t)NH * NCH * FDM);

    F2BArgs fa;
    fa.src[0] = hs; fa.dst[0] = hsb; fa.n[0] = (int)SZ;
    fa.src[1] = Wq; fa.dst[1] = wqb; fa.n[1] = (int)WZ;
    fa.src[2] = Wk; fa.dst[2] = wkb; fa.n[2] = (int)WZ;
    fa.src[3] = Wv; fa.dst[3] = wvb; fa.n[3] = (int)WZ;
    fa.src[4] = Wo; fa.dst[4] = wob; fa.n[4] = (int)WZ;
    f2b_multi<<<dim3((unsigned)(WZ / 1024), 5), 256, 0, stream>>>(fa);

    wf_transpose<<<dim3(NH, 2), 256, 0, stream>>>(Wfq, Wfk, WfqT, WfkT);

    // 64x128 tile: grid 16 x 16 x 3 = 768 blocks = 3 blocks/CU
    gemm_qkv<<<dim3(HID / 128, LQ / 64, 3), 256, 0, stream>>>(hsb, wqb, wkb, wvb, qb2, kb2, vb2);

    featmap_chunk<<<dim3(NCH, NH, 2), 256, 0, stream>>>(qb2, kb2, vb2, WfqT, WfkT,
                                                        fqB, fkB, VTb, Sraw, Ks);

    prefix2<<<dim3(NH, 8), 256, 0, stream>>>(Sraw, SpreB, Ks, Kpre);

    intra2<<<dim3(NCH, NH), 256, 0, stream>>>(fqB, fkB, VTb, SpreB, Kpre, Yb);

    gemm_one<<<dim3(HID / 128, LQ / 64), 256, 0, stream>>>(Yb, wob, out);
}

// Round 5
// 198.451 us; speedup vs baseline: 4.3959x; 1.0721x over previous
//
#include <hip/hip_runtime.h>
#include <math.h>

// Problem constants
constexpr int LQ  = 1024;   // sequence length
constexpr int NH  = 32;     // heads
constexpr int HDM = 64;     // head dim
constexpr int FDM = 64;     // feature dim
constexpr int HID = 2048;   // NH*HDM
constexpr int NCH = 16;     // chunks
constexpr int CT  = 64;     // chunk length (NCH*CT == LQ)
#define EPSV 1e-12f

typedef __bf16 bf16x8 __attribute__((ext_vector_type(8)));
typedef float  f32x4  __attribute__((ext_vector_type(4)));

// fp32 -> bf16 raw bits, round-to-nearest-even
__device__ __forceinline__ unsigned short f2b_raw(float x) {
    union { float f; unsigned int u; } v; v.f = x;
    unsigned int r = v.u + 0x7fffu + ((v.u >> 16) & 1u);
    return (unsigned short)(r >> 16);
}
__device__ __forceinline__ float b2f(ushort u) {
    union { unsigned int i; float f; } v; v.i = ((unsigned int)u) << 16; return v.f;
}

// async global->LDS, 16B per lane; lds dst = wave-uniform base + lane*16
#define ASYNC16(ldsp, gp) __builtin_amdgcn_global_load_lds( \
    (const __attribute__((address_space(1))) void*)(gp),    \
    (__attribute__((address_space(3))) void*)(ldsp), 16, 0, 0)

// ---------------------------------------------------------------------------
// bf16 MFMA GEMM (NT): C[M,N] = A[M,K] * B[N,K]^T. A,B bf16 raw (ushort).
// TM x TN tile, BK=64, 256 threads = 4 waves (2x2), double-buffered LDS with
// one barrier per iter (loads for it+1 in flight during compute of it).
// LDS rows are 64 elems (128 B) with XOR-8 chunk swizzle applied on the
// GLOBAL address so global_load_lds(16B) stays contiguous while fragment
// ds_read_b128s land 2-way-per-bank (free).
// ---------------------------------------------------------------------------
template <int TM, int TN, bool BF16OUT>
__device__ __forceinline__ void gemm_core(const ushort* __restrict__ A,
                                          const ushort* __restrict__ B,
                                          void* __restrict__ Cv,
                                          int M, int N, int K) {
    constexpr int FI = TM / 32, FJ = TN / 32;   // frag tiles per wave
    constexpr int AI = TM / 32, BJ = TN / 32;   // stage instrs per wave
    constexpr int ASZ = TM * 64, BSZ = TN * 64;
    __shared__ __align__(16) ushort As[2 * ASZ];
    __shared__ __align__(16) ushort Bs[2 * BSZ];

    const int t = threadIdx.x, wave = t >> 6, lane = t & 63;
    const int wr = (wave >> 1) * (TM / 2), wc = (wave & 1) * (TN / 2);
    const int bm = blockIdx.y * TM, bn = blockIdx.x * TN;

    // staging geometry: each instr covers 8 rows x 64 elems (1 KB);
    // lane -> row = lane>>3, 16B-chunk = (lane&7) ^ (row&7)  (XOR swizzle)
    const int grow = lane >> 3;
    const int gsw  = ((lane & 7) ^ (grow & 7)) << 3;   // element offset
    const int arow0 = wave * (TM / 4), brow0 = wave * (TN / 4);
    const ushort* gA = A + (size_t)(bm + arow0 + grow) * K + gsw;
    const ushort* gB = B + (size_t)(bn + brow0 + grow) * K + gsw;

    const int fr = lane & 15, q = lane >> 4;

    f32x4 acc[FI][FJ] = {};
    const int NIT = K >> 6;

    // prologue: stage iter 0 into buf 0
    {
        ushort* ab = As + arow0 * 64;
        ushort* bb = Bs + brow0 * 64;
#pragma unroll
        for (int i = 0; i < AI; ++i) ASYNC16(ab + i * 512, gA + (size_t)i * 8 * K);
#pragma unroll
        for (int j = 0; j < BJ; ++j) ASYNC16(bb + j * 512, gB + (size_t)j * 8 * K);
    }
    __syncthreads();

    for (int it = 0; it < NIT; ++it) {
        const int p = it & 1;
        if (it + 1 < NIT) {   // stage next iter into other buffer (overlaps compute)
            const int ko = (it + 1) << 6;
            ushort* ab = As + (p ^ 1) * ASZ + arow0 * 64;
            ushort* bb = Bs + (p ^ 1) * BSZ + brow0 * 64;
#pragma unroll
            for (int i = 0; i < AI; ++i) ASYNC16(ab + i * 512, gA + ko + (size_t)i * 8 * K);
#pragma unroll
            for (int j = 0; j < BJ; ++j) ASYNC16(bb + j * 512, gB + ko + (size_t)j * 8 * K);
        }
        // compute from buf p
        const ushort* ap = As + p * ASZ;
        const ushort* bp = Bs + p * BSZ;
        bf16x8 af[2][FI], bg[2][FJ];
#pragma unroll
        for (int ks = 0; ks < 2; ++ks) {
#pragma unroll
            for (int i = 0; i < FI; ++i) {
                const int row = wr + i * 16 + fr;
                af[ks][i] = *(const bf16x8*)&ap[row * 64 + ((((q + ks * 4)) ^ (row & 7)) << 3)];
            }
#pragma unroll
            for (int j = 0; j < FJ; ++j) {
                const int row = wc + j * 16 + fr;
                bg[ks][j] = *(const bf16x8*)&bp[row * 64 + ((((q + ks * 4)) ^ (row & 7)) << 3)];
            }
        }
#pragma unroll
        for (int ks = 0; ks < 2; ++ks)
#pragma unroll
            for (int i = 0; i < FI; ++i)
#pragma unroll
                for (int j = 0; j < FJ; ++j)
                    acc[i][j] = __builtin_amdgcn_mfma_f32_16x16x32_bf16(af[ks][i], bg[ks][j], acc[i][j], 0, 0, 0);
        if (it + 1 < NIT) __syncthreads();   // drains next-iter loads; protects buf p
    }

    // epilogue: C/D layout col=lane&15, row=(lane>>4)*4+reg
    const int er = q * 4;
    const int ec = lane & 15;
#pragma unroll
    for (int i = 0; i < FI; ++i)
#pragma unroll
        for (int j = 0; j < FJ; ++j) {
            const size_t base = (size_t)(bm + wr + i * 16 + er) * N + bn + wc + j * 16 + ec;
            if constexpr (BF16OUT) {
                ushort* C = (ushort*)Cv;
#pragma unroll
                for (int r = 0; r < 4; ++r) C[base + (size_t)r * N] = f2b_raw(acc[i][j][r]);
            } else {
                float* C = (float*)Cv;
#pragma unroll
                for (int r = 0; r < 4; ++r) C[base + (size_t)r * N] = acc[i][j][r];
            }
        }
}

__global__ __launch_bounds__(256) void gemm_qkv(const ushort* __restrict__ hsb,
                                                const ushort* __restrict__ wqb,
                                                const ushort* __restrict__ wkb,
                                                const ushort* __restrict__ wvb,
                                                ushort* __restrict__ qb,
                                                ushort* __restrict__ kb,
                                                ushort* __restrict__ vb) {
    const ushort* B; ushort* C;
    if (blockIdx.z == 0)      { B = wqb; C = qb; }
    else if (blockIdx.z == 1) { B = wkb; C = kb; }
    else                      { B = wvb; C = vb; }
    gemm_core<64, 128, true>(hsb, B, C, LQ, HID, HID);
}

__global__ __launch_bounds__(256) void gemm_one(const ushort* __restrict__ A,
                                                const ushort* __restrict__ B,
                                                float* __restrict__ C) {
    gemm_core<64, 64, false>(A, B, C, LQ, HID, HID);
}

// ---------------------------------------------------------------------------
// fp32 -> bf16 conversion, 5 tensors in one dispatch
// ---------------------------------------------------------------------------
struct F2BArgs { const float* src[5]; ushort* dst[5]; int n[5]; };
__global__ __launch_bounds__(256) void f2b_multi(F2BArgs p) {
    const int which = blockIdx.y;
    const float* s = p.src[which];
    ushort* d = p.dst[which];
    const int n = p.n[which];
    const int i = (blockIdx.x * 256 + threadIdx.x) * 4;
    if (i >= n) return;
    float4 v = *(const float4*)&s[i];
    ushort4 o = make_ushort4(f2b_raw(v.x), f2b_raw(v.y), f2b_raw(v.z), f2b_raw(v.w));
    *(ushort4*)&d[i] = o;
}

// ---------------------------------------------------------------------------
// Wf [h][d][f] fp32  ->  WfT [h][f][d] bf16.  grid (NH, 2), block 256.
// ---------------------------------------------------------------------------
__global__ __launch_bounds__(256) void wf_transpose(const float* __restrict__ Wfq,
                                                    const float* __restrict__ Wfk,
                                                    ushort* __restrict__ WfqT,
                                                    ushort* __restrict__ WfkT) {
    const int h = blockIdx.x, isK = blockIdx.y;
    const float* src = (isK ? Wfk : Wfq) + (size_t)h * 4096;   // [d][f]
    ushort* dst = (isK ? WfkT : WfqT) + (size_t)h * 4096;      // [f][d]
    __shared__ float tile[64][65];
    const int t = threadIdx.x;
    for (int it = 0; it < 16; ++it) {
        int e = it * 256 + t; int d = e >> 6, f = e & 63;
        tile[d][f] = src[e];
    }
    __syncthreads();
    for (int it = 0; it < 16; ++it) {
        int e = it * 256 + t; int f = e >> 6, d = e & 63;
        dst[e] = f2b_raw(tile[d][f]);
    }
}

// ---------------------------------------------------------------------------
// Feature map per (chunk, head, q|k) via MFMA + fused chunk-state (k branch).
// ---------------------------------------------------------------------------
__global__ __launch_bounds__(256) void featmap_chunk(
    const ushort* __restrict__ qb, const ushort* __restrict__ kb,
    const ushort* __restrict__ vb,
    const ushort* __restrict__ WfqT, const ushort* __restrict__ WfkT,
    ushort* __restrict__ fqB, ushort* __restrict__ fkB,
    ushort* __restrict__ VTb, float* __restrict__ Sraw, float* __restrict__ Ks) {
    __shared__ __align__(16) ushort Xs[64 * 72];
    __shared__ __align__(16) ushort Ws[64 * 72];
    __shared__ float Zs[64][68];
    __shared__ __align__(16) ushort Fs[64 * 72];
    __shared__ __align__(16) ushort Vs[64 * 72];

    const int c = blockIdx.x, h = blockIdx.y, isK = blockIdx.z;
    const int t = threadIdx.x, lane = t & 63, wave = t >> 6;
    const int l0 = c * CT;
    const int fr = lane & 15, fo = (lane >> 4) * 8;
    const int g = lane >> 4, cc = lane & 15;

    const ushort* X  = (isK ? kb : qb);
    const ushort* WT = (isK ? WfkT : WfqT) + (size_t)h * 4096;

    for (int it = 0; it < 2; ++it) {
        int e = (it * 256 + t) * 8;
        int row = e >> 6, col = e & 63;
        *(uint4*)&Xs[row * 72 + col] = *(const uint4*)&X[(size_t)(l0 + row) * HID + h * HDM + col];
        *(uint4*)&Ws[row * 72 + col] = *(const uint4*)&WT[e];
        if (isK) {
            uint4 vv = *(const uint4*)&vb[(size_t)(l0 + row) * HID + h * HDM + col];
            const ushort* pv = (const ushort*)&vv;
#pragma unroll
            for (int i = 0; i < 8; ++i) Vs[(col + i) * 72 + row] = pv[i];
        }
    }
    __syncthreads();

    // Z = X @ WT^T
    f32x4 accZ[4] = {};
#pragma unroll
    for (int kp = 0; kp < 2; ++kp) {
        bf16x8 a = *(const bf16x8*)&Xs[(wave * 16 + fr) * 72 + kp * 32 + fo];
#pragma unroll
        for (int j = 0; j < 4; ++j) {
            bf16x8 b = *(const bf16x8*)&Ws[(j * 16 + fr) * 72 + kp * 32 + fo];
            accZ[j] = __builtin_amdgcn_mfma_f32_16x16x32_bf16(a, b, accZ[j], 0, 0, 0);
        }
    }
#pragma unroll
    for (int j = 0; j < 4; ++j)
#pragma unroll
        for (int r = 0; r < 4; ++r)
            Zs[wave * 16 + g * 4 + r][j * 16 + cc] = accZ[j][r];
    __syncthreads();

    // softmax over f (64) per row; 4 threads/row
    const int srow = t >> 2, spart = t & 3;
    float zv[16], m = -1e30f;
#pragma unroll
    for (int i = 0; i < 16; ++i) { zv[i] = Zs[srow][spart * 16 + i]; m = fmaxf(m, zv[i]); }
    m = fmaxf(m, __shfl_xor(m, 1)); m = fmaxf(m, __shfl_xor(m, 2));
    float s = 0.f;
#pragma unroll
    for (int i = 0; i < 16; ++i) { zv[i] = __expf(zv[i] - m); s += zv[i]; }
    s += __shfl_xor(s, 1); s += __shfl_xor(s, 2);
    const float inv = 1.0f / s;
    ushort ov[16];
#pragma unroll
    for (int i = 0; i < 16; ++i) ov[i] = f2b_raw(zv[i] * inv);
    ushort* outp = (isK ? fkB : fqB) + ((size_t)h * LQ + l0 + srow) * FDM + spart * 16;
    *(uint4*)&outp[0] = *(uint4*)&ov[0];
    *(uint4*)&outp[8] = *(uint4*)&ov[8];
    if (isK) {
#pragma unroll
        for (int i = 0; i < 16; ++i) Fs[(spart * 16 + i) * 72 + srow] = ov[i];
    }
    if (!isK) return;
    __syncthreads();

    // Ks column sums
    if (t < 64) {
        float ks = 0.f;
#pragma unroll 8
        for (int l = 0; l < 64; ++l) ks += b2f(Fs[t * 72 + l]);
        Ks[((size_t)h * NCH + c) * FDM + t] = ks;
    }
    // VT global copy
    const size_t cb = ((size_t)h * NCH + c) * 4096;
    for (int it = 0; it < 2; ++it) {
        int e = (it * 256 + t) * 8;
        int row = e >> 6, col = e & 63;
        *(uint4*)&VTb[cb + e] = *(const uint4*)&Vs[row * 72 + col];
    }
    // St[d][f] = VT @ Fs^T
    f32x4 accS[4] = {};
#pragma unroll
    for (int kp = 0; kp < 2; ++kp) {
        bf16x8 a = *(const bf16x8*)&Vs[(wave * 16 + fr) * 72 + kp * 32 + fo];
#pragma unroll
        for (int j = 0; j < 4; ++j) {
            bf16x8 b = *(const bf16x8*)&Fs[(j * 16 + fr) * 72 + kp * 32 + fo];
            accS[j] = __builtin_amdgcn_mfma_f32_16x16x32_bf16(a, b, accS[j], 0, 0, 0);
        }
    }
    float* sp = Sraw + cb;
#pragma unroll
    for (int j = 0; j < 4; ++j)
#pragma unroll
        for (int r = 0; r < 4; ++r)
            sp[(wave * 16 + g * 4 + r) * 64 + j * 16 + cc] = accS[j][r];
}

// ---------------------------------------------------------------------------
// Exclusive prefix over chunks; parallelized: grid (NH, 8), block 256.
// ---------------------------------------------------------------------------
__global__ __launch_bounds__(256) void prefix2(const float* __restrict__ Sraw,
                                               ushort* __restrict__ SpreB,
                                               const float* __restrict__ Ks,
                                               float* __restrict__ Kpre) {
    const int h = blockIdx.x, eb = blockIdx.y, t = threadIdx.x;
    const int e0 = eb * 512 + t * 2;
    float r0 = 0.f, r1 = 0.f;
    const size_t hb = (size_t)h * NCH * 4096;
    for (int c2 = 0; c2 < NCH; ++c2) {
        const size_t base = hb + (size_t)c2 * 4096 + e0;
        float c0 = Sraw[base], c1 = Sraw[base + 1];
        ushort2 o = make_ushort2(f2b_raw(r0), f2b_raw(r1));
        *(ushort2*)&SpreB[base] = o;
        r0 += c0; r1 += c1;
    }
    if (eb == 0 && t < 64) {
        float rk = 0.f;
        for (int c2 = 0; c2 < NCH; ++c2) {
            const size_t kb2 = ((size_t)h * NCH + c2) * FDM + t;
            float cur = Ks[kb2];
            Kpre[kb2] = rk;
            rk += cur;
        }
    }
}

// ---------------------------------------------------------------------------
// Intra-chunk attention via MFMA.
// ---------------------------------------------------------------------------
__global__ __launch_bounds__(256) void intra2(
    const ushort* __restrict__ fqB, const ushort* __restrict__ fkB,
    const ushort* __restrict__ VTb, const ushort* __restrict__ SpreB,
    const float* __restrict__ Kpre, ushort* __restrict__ Yb) {
    __shared__ __align__(16) ushort fqs[64 * 72];
    __shared__ __align__(16) ushort fks[64 * 72];
    __shared__ __align__(16) ushort VTs[64 * 72];
    __shared__ __align__(16) ushort Sps[64 * 72];
    __shared__ __align__(16) ushort Pms[64 * 72];
    __shared__ float den[64], kpr[64];

    const int c = blockIdx.x, h = blockIdx.y;
    const int t = threadIdx.x, lane = t & 63, wave = t >> 6;
    const int l0 = c * CT;
    const int fr = lane & 15, fo = (lane >> 4) * 8;
    const int g = lane >> 4, cc = lane & 15;

    const size_t qkbase = ((size_t)h * LQ + l0) * FDM;
    const size_t cbase  = ((size_t)h * NCH + c) * 4096;
    for (int it = 0; it < 2; ++it) {
        int e = (it * 256 + t) * 8;
        int row = e >> 6, col = e & 63;
        *(uint4*)&fqs[row * 72 + col] = *(const uint4*)&fqB[qkbase + e];
        *(uint4*)&fks[row * 72 + col] = *(const uint4*)&fkB[qkbase + e];
        *(uint4*)&VTs[row * 72 + col] = *(const uint4*)&VTb[cbase + e];
        *(uint4*)&Sps[row * 72 + col] = *(const uint4*)&SpreB[cbase + e];
    }
    if (t < 64) kpr[t] = Kpre[((size_t)h * NCH + c) * FDM + t];
    __syncthreads();

    // P = fq @ fk^T
    f32x4 accP[4] = {};
#pragma unroll
    for (int kp = 0; kp < 2; ++kp) {
        bf16x8 a = *(const bf16x8*)&fqs[(wave * 16 + fr) * 72 + kp * 32 + fo];
#pragma unroll
        for (int j = 0; j < 4; ++j) {
            bf16x8 b = *(const bf16x8*)&fks[(j * 16 + fr) * 72 + kp * 32 + fo];
            accP[j] = __builtin_amdgcn_mfma_f32_16x16x32_bf16(a, b, accP[j], 0, 0, 0);
        }
    }
#pragma unroll
    for (int j = 0; j < 4; ++j)
#pragma unroll
        for (int r = 0; r < 4; ++r) {
            int l = wave * 16 + g * 4 + r, lp = j * 16 + cc;
            Pms[l * 72 + lp] = (lp <= l) ? f2b_raw(accP[j][r]) : (ushort)0;
        }
    __syncthreads();

    // denominator, 4 threads/row
    {
        const int srow = t >> 2, spart = t & 3;
        float s = 0.f;
#pragma unroll
        for (int i = 0; i < 16; ++i) s += b2f(Pms[srow * 72 + spart * 16 + i]);
#pragma unroll
        for (int i = 0; i < 16; ++i) s += b2f(fqs[srow * 72 + spart * 16 + i]) * kpr[spart * 16 + i];
        s += __shfl_xor(s, 1); s += __shfl_xor(s, 2);
        if (spart == 0) den[srow] = s + EPSV;
    }
    __syncthreads();

    // Y = Pm @ V + fq @ Spre^T
    f32x4 accY[4] = {};
#pragma unroll
    for (int kp = 0; kp < 2; ++kp) {
        bf16x8 a = *(const bf16x8*)&Pms[(wave * 16 + fr) * 72 + kp * 32 + fo];
#pragma unroll
        for (int j = 0; j < 4; ++j) {
            bf16x8 b = *(const bf16x8*)&VTs[(j * 16 + fr) * 72 + kp * 32 + fo];
            accY[j] = __builtin_amdgcn_mfma_f32_16x16x32_bf16(a, b, accY[j], 0, 0, 0);
        }
    }
#pragma unroll
    for (int kp = 0; kp < 2; ++kp) {
        bf16x8 a = *(const bf16x8*)&fqs[(wave * 16 + fr) * 72 + kp * 32 + fo];
#pragma unroll
        for (int j = 0; j < 4; ++j) {
            bf16x8 b = *(const bf16x8*)&Sps[(j * 16 + fr) * 72 + kp * 32 + fo];
            accY[j] = __builtin_amdgcn_mfma_f32_16x16x32_bf16(a, b, accY[j], 0, 0, 0);
        }
    }
#pragma unroll
    for (int r = 0; r < 4; ++r) {
        int l = wave * 16 + g * 4 + r;
        float inv = 1.0f / den[l];
        ushort* yo = Yb + (size_t)(l0 + l) * HID + h * HDM;
#pragma unroll
        for (int j = 0; j < 4; ++j)
            yo[j * 16 + cc] = f2b_raw(accY[j][r] * inv);
    }
}

// ---------------------------------------------------------------------------
extern "C" void kernel_launch(void* const* d_in, const int* in_sizes, int n_in,
                              void* d_out, int out_size, void* d_ws, size_t ws_size,
                              hipStream_t stream) {
    const float* hs  = (const float*)d_in[0];
    const float* Wq  = (const float*)d_in[1];
    const float* Wk  = (const float*)d_in[2];
    const float* Wv  = (const float*)d_in[3];
    const float* Wo  = (const float*)d_in[4];
    const float* Wfq = (const float*)d_in[5];
    const float* Wfk = (const float*)d_in[6];
    float* out = (float*)d_out;

    const size_t SZ = (size_t)LQ * HID;          // 2,097,152
    const size_t WZ = (size_t)HID * HID;         // 4,194,304

    char* w = (char*)d_ws;
    auto aus = [&](size_t n) { ushort* p = (ushort*)w; w += n * sizeof(ushort); return p; };
    auto afl = [&](size_t n) { float*  p = (float*)w;  w += n * sizeof(float);  return p; };

    ushort* hsb   = aus(SZ);
    ushort* wqb   = aus(WZ);
    ushort* wkb   = aus(WZ);
    ushort* wvb   = aus(WZ);
    ushort* wob   = aus(WZ);
    ushort* qb2   = aus(SZ);
    ushort* kb2   = aus(SZ);
    ushort* vb2   = aus(SZ);
    ushort* fqB   = aus(SZ);
    ushort* fkB   = aus(SZ);
    ushort* VTb   = aus(SZ);
    ushort* WfqT  = aus((size_t)NH * 4096);
    ushort* WfkT  = aus((size_t)NH * 4096);
    ushort* SpreB = aus(SZ);
    ushort* Yb    = aus(SZ);
    float*  Sraw  = afl(SZ);
    float*  Ks    = afl((size_t)NH * NCH * FDM);
    float*  Kpre  = afl((size_t)NH * NCH * FDM);

    F2BArgs fa;
    fa.src[0] = hs; fa.dst[0] = hsb; fa.n[0] = (int)SZ;
    fa.src[1] = Wq; fa.dst[1] = wqb; fa.n[1] = (int)WZ;
    fa.src[2] = Wk; fa.dst[2] = wkb; fa.n[2] = (int)WZ;
    fa.src[3] = Wv; fa.dst[3] = wvb; fa.n[3] = (int)WZ;
    fa.src[4] = Wo; fa.dst[4] = wob; fa.n[4] = (int)WZ;
    f2b_multi<<<dim3((unsigned)(WZ / 1024), 5), 256, 0, stream>>>(fa);

    wf_transpose<<<dim3(NH, 2), 256, 0, stream>>>(Wfq, Wfk, WfqT, WfkT);

    // 64x128 tile: grid 16 x 16 x 3 = 768 blocks = 3 blocks/CU
    gemm_qkv<<<dim3(HID / 128, LQ / 64, 3), 256, 0, stream>>>(hsb, wqb, wkb, wvb, qb2, kb2, vb2);

    featmap_chunk<<<dim3(NCH, NH, 2), 256, 0, stream>>>(qb2, kb2, vb2, WfqT, WfkT,
                                                        fqB, fkB, VTb, Sraw, Ks);

    prefix2<<<dim3(NH, 8), 256, 0, stream>>>(Sraw, SpreB, Ks, Kpre);

    intra2<<<dim3(NCH, NH), 256, 0, stream>>>(fqB, fkB, VTb, SpreB, Kpre, Yb);

    // 64x64 tile: grid 32 x 16 = 512 blocks = 2 blocks/CU
    gemm_one<<<dim3(HID / 64, LQ / 64), 256, 0, stream>>>(Yb, wob, out);
}

// Round 6
// 195.144 us; speedup vs baseline: 4.4704x; 1.0169x over previous
//
#include <hip/hip_runtime.h>
#include <math.h>

// Problem constants
constexpr int LQ  = 1024;   // sequence length
constexpr int NH  = 32;     // heads
constexpr int HDM = 64;     // head dim
constexpr int FDM = 64;     // feature dim
constexpr int HID = 2048;   // NH*HDM
constexpr int NCH = 16;     // chunks
constexpr int CT  = 64;     // chunk length (NCH*CT == LQ)
#define EPSV 1e-12f

typedef __bf16 bf16x8 __attribute__((ext_vector_type(8)));
typedef float  f32x4  __attribute__((ext_vector_type(4)));

// fp32 -> bf16 raw bits, round-to-nearest-even
__device__ __forceinline__ unsigned short f2b_raw(float x) {
    union { float f; unsigned int u; } v; v.f = x;
    unsigned int r = v.u + 0x7fffu + ((v.u >> 16) & 1u);
    return (unsigned short)(r >> 16);
}
__device__ __forceinline__ float b2f(ushort u) {
    union { unsigned int i; float f; } v; v.i = ((unsigned int)u) << 16; return v.f;
}

// async global->LDS, 16B per lane; lds dst = wave-uniform base + lane*16
#define ASYNC16(ldsp, gp) __builtin_amdgcn_global_load_lds( \
    (const __attribute__((address_space(1))) void*)(gp),    \
    (__attribute__((address_space(3))) void*)(ldsp), 16, 0, 0)

// ---------------------------------------------------------------------------
// Generic bf16 MFMA GEMM core (NT), BK=64, double-buffered, XOR-swizzled LDS.
// Used only by gemm_one now.
// ---------------------------------------------------------------------------
template <int TM, int TN, bool BF16OUT>
__device__ __forceinline__ void gemm_core(const ushort* __restrict__ A,
                                          const ushort* __restrict__ B,
                                          void* __restrict__ Cv,
                                          int M, int N, int K) {
    constexpr int FI = TM / 32, FJ = TN / 32;
    constexpr int AI = TM / 32, BJ = TN / 32;
    constexpr int ASZ = TM * 64, BSZ = TN * 64;
    __shared__ __align__(16) ushort As[2 * ASZ];
    __shared__ __align__(16) ushort Bs[2 * BSZ];

    const int t = threadIdx.x, wave = t >> 6, lane = t & 63;
    const int wr = (wave >> 1) * (TM / 2), wc = (wave & 1) * (TN / 2);
    const int bm = blockIdx.y * TM, bn = blockIdx.x * TN;

    const int grow = lane >> 3;
    const int gsw  = ((lane & 7) ^ (grow & 7)) << 3;
    const int arow0 = wave * (TM / 4), brow0 = wave * (TN / 4);
    const ushort* gA = A + (size_t)(bm + arow0 + grow) * K + gsw;
    const ushort* gB = B + (size_t)(bn + brow0 + grow) * K + gsw;

    const int fr = lane & 15, q = lane >> 4;

    f32x4 acc[FI][FJ] = {};
    const int NIT = K >> 6;

    {
        ushort* ab = As + arow0 * 64;
        ushort* bb = Bs + brow0 * 64;
#pragma unroll
        for (int i = 0; i < AI; ++i) ASYNC16(ab + i * 512, gA + (size_t)i * 8 * K);
#pragma unroll
        for (int j = 0; j < BJ; ++j) ASYNC16(bb + j * 512, gB + (size_t)j * 8 * K);
    }
    __syncthreads();

    for (int it = 0; it < NIT; ++it) {
        const int p = it & 1;
        if (it + 1 < NIT) {
            const int ko = (it + 1) << 6;
            ushort* ab = As + (p ^ 1) * ASZ + arow0 * 64;
            ushort* bb = Bs + (p ^ 1) * BSZ + brow0 * 64;
#pragma unroll
            for (int i = 0; i < AI; ++i) ASYNC16(ab + i * 512, gA + ko + (size_t)i * 8 * K);
#pragma unroll
            for (int j = 0; j < BJ; ++j) ASYNC16(bb + j * 512, gB + ko + (size_t)j * 8 * K);
        }
        const ushort* ap = As + p * ASZ;
        const ushort* bp = Bs + p * BSZ;
        bf16x8 af[2][FI], bg[2][FJ];
#pragma unroll
        for (int ks = 0; ks < 2; ++ks) {
#pragma unroll
            for (int i = 0; i < FI; ++i) {
                const int row = wr + i * 16 + fr;
                af[ks][i] = *(const bf16x8*)&ap[row * 64 + (((q + ks * 4) ^ (row & 7)) << 3)];
            }
#pragma unroll
            for (int j = 0; j < FJ; ++j) {
                const int row = wc + j * 16 + fr;
                bg[ks][j] = *(const bf16x8*)&bp[row * 64 + (((q + ks * 4) ^ (row & 7)) << 3)];
            }
        }
#pragma unroll
        for (int ks = 0; ks < 2; ++ks)
#pragma unroll
            for (int i = 0; i < FI; ++i)
#pragma unroll
                for (int j = 0; j < FJ; ++j)
                    acc[i][j] = __builtin_amdgcn_mfma_f32_16x16x32_bf16(af[ks][i], bg[ks][j], acc[i][j], 0, 0, 0);
        if (it + 1 < NIT) __syncthreads();
    }

    const int er = q * 4, ec = lane & 15;
#pragma unroll
    for (int i = 0; i < FI; ++i)
#pragma unroll
        for (int j = 0; j < FJ; ++j) {
            const size_t base = (size_t)(bm + wr + i * 16 + er) * N + bn + wc + j * 16 + ec;
            if constexpr (BF16OUT) {
                ushort* C = (ushort*)Cv;
#pragma unroll
                for (int r = 0; r < 4; ++r) C[base + (size_t)r * N] = f2b_raw(acc[i][j][r]);
            } else {
                float* C = (float*)Cv;
#pragma unroll
                for (int r = 0; r < 4; ++r) C[base + (size_t)r * N] = acc[i][j][r];
            }
        }
}

__global__ __launch_bounds__(256) void gemm_one(const ushort* __restrict__ A,
                                                const ushort* __restrict__ B,
                                                float* __restrict__ C) {
    gemm_core<64, 64, false>(A, B, C, LQ, HID, HID);
}

// ---------------------------------------------------------------------------
// Fused QKV projection + feature map (z=0: Q->fqB, z=1: K->fkB) or
// transposed V store (z=2: ->VTb [h][c][d][l]).
// Tile 64(M=one chunk) x 128(N=two heads), BK=64, dbuf, XOR swizzle.
// ---------------------------------------------------------------------------
__global__ __launch_bounds__(256) void gemm_qkv_fm(
    const ushort* __restrict__ hsb,
    const ushort* __restrict__ wqb, const ushort* __restrict__ wkb,
    const ushort* __restrict__ wvb,
    const ushort* __restrict__ WfqT, const ushort* __restrict__ WfkT,
    ushort* __restrict__ fqB, ushort* __restrict__ fkB,
    ushort* __restrict__ VTb) {
    constexpr int TM = 64, TN = 128;
    constexpr int ASZ = TM * 64, BSZ = TN * 64;       // 4096 / 8192 ushort
    __shared__ __align__(16) ushort lds[2 * ASZ + 2 * BSZ];   // 24576 ushort = 48 KB
    ushort* As = lds;
    ushort* Bs = lds + 2 * ASZ;

    const int z = blockIdx.z;
    const ushort* Bmat = (z == 0) ? wqb : (z == 1) ? wkb : wvb;

    const int t = threadIdx.x, wave = t >> 6, lane = t & 63;
    const int wr = (wave >> 1) * 32, wc = (wave & 1) * 64;
    const int bx = blockIdx.x, c = blockIdx.y;
    const int bm = c * TM, bn = bx * TN, l0 = c * CT;

    const int grow = lane >> 3;
    const int gsw  = ((lane & 7) ^ (grow & 7)) << 3;
    const int arow0 = wave * 16, brow0 = wave * 32;
    const ushort* gA = hsb  + (size_t)(bm + arow0 + grow) * HID + gsw;
    const ushort* gB = Bmat + (size_t)(bn + brow0 + grow) * HID + gsw;

    const int fr = lane & 15, q = lane >> 4, ec = lane & 15;

    f32x4 acc[2][4] = {};
    const int NIT = HID >> 6;   // 32

    {
        ushort* ab = As + arow0 * 64;
        ushort* bb = Bs + brow0 * 64;
#pragma unroll
        for (int i = 0; i < 2; ++i) ASYNC16(ab + i * 512, gA + (size_t)i * 8 * HID);
#pragma unroll
        for (int j = 0; j < 4; ++j) ASYNC16(bb + j * 512, gB + (size_t)j * 8 * HID);
    }
    __syncthreads();

    for (int it = 0; it < NIT; ++it) {
        const int p = it & 1;
        if (it + 1 < NIT) {
            const int ko = (it + 1) << 6;
            ushort* ab = As + (p ^ 1) * ASZ + arow0 * 64;
            ushort* bb = Bs + (p ^ 1) * BSZ + brow0 * 64;
#pragma unroll
            for (int i = 0; i < 2; ++i) ASYNC16(ab + i * 512, gA + ko + (size_t)i * 8 * HID);
#pragma unroll
            for (int j = 0; j < 4; ++j) ASYNC16(bb + j * 512, gB + ko + (size_t)j * 8 * HID);
        }
        const ushort* ap = As + p * ASZ;
        const ushort* bp = Bs + p * BSZ;
        bf16x8 af[2][2], bg[2][4];
#pragma unroll
        for (int ks = 0; ks < 2; ++ks) {
#pragma unroll
            for (int i = 0; i < 2; ++i) {
                const int row = wr + i * 16 + fr;
                af[ks][i] = *(const bf16x8*)&ap[row * 64 + (((q + ks * 4) ^ (row & 7)) << 3)];
            }
#pragma unroll
            for (int j = 0; j < 4; ++j) {
                const int row = wc + j * 16 + fr;
                bg[ks][j] = *(const bf16x8*)&bp[row * 64 + (((q + ks * 4) ^ (row & 7)) << 3)];
            }
        }
#pragma unroll
        for (int ks = 0; ks < 2; ++ks)
#pragma unroll
            for (int i = 0; i < 2; ++i)
#pragma unroll
                for (int j = 0; j < 4; ++j)
                    acc[i][j] = __builtin_amdgcn_mfma_f32_16x16x32_bf16(af[ks][i], bg[ks][j], acc[i][j], 0, 0, 0);
        if (it + 1 < NIT) __syncthreads();
    }

    if (z == 2) {
        // transposed V store: r is contiguous in l -> ushort4
#pragma unroll
        for (int i = 0; i < 2; ++i)
#pragma unroll
            for (int j = 0; j < 4; ++j) {
                const int col = wc + j * 16 + ec;        // 0..127
                const int hh = col >> 6, d = col & 63;
                const int lb = wr + i * 16 + q * 4;
                const size_t base = (((size_t)(2 * bx + hh) * NCH + c) * 64 + d) * 64 + lb;
                ushort4 o = make_ushort4(f2b_raw(acc[i][j][0]), f2b_raw(acc[i][j][1]),
                                         f2b_raw(acc[i][j][2]), f2b_raw(acc[i][j][3]));
                *(ushort4*)&VTb[base] = o;
            }
        return;
    }

    // ---- fused feature map ----
    __syncthreads();                       // all LDS reads of K-loop done
    ushort* Qt  = lds;                     // [64][136] bf16 projection tile
    ushort* Wfs = lds + 8704;              // [2][64][72] WfT for heads 2bx,2bx+1
#pragma unroll
    for (int i = 0; i < 2; ++i)
#pragma unroll
        for (int j = 0; j < 4; ++j)
#pragma unroll
            for (int r = 0; r < 4; ++r)
                Qt[(wr + i * 16 + q * 4 + r) * 136 + wc + j * 16 + ec] = f2b_raw(acc[i][j][r]);
    {
        const ushort* WT = ((z == 0) ? WfqT : WfkT) + (size_t)(2 * bx) * 4096;
#pragma unroll
        for (int it = 0; it < 4; ++it) {
            const int e = it * 2048 + t * 8;
            const int hh = e >> 12, f = (e >> 6) & 63, dc = e & 63;
            uint4 wv4 = *(const uint4*)&WT[e];
            *(uint4*)&Wfs[hh * 4608 + f * 72 + dc] = wv4;
        }
    }
    __syncthreads();

    // Z = Qhead @ WfT^T  : wave -> head (wave&1), rows (wave>>1)*32..+32
    const int hh = wave & 1, R0 = (wave >> 1) * 32;
    f32x4 z2[2][4] = {};
#pragma unroll
    for (int ks = 0; ks < 2; ++ks) {
        bf16x8 a[2];
#pragma unroll
        for (int i = 0; i < 2; ++i)
            a[i] = *(const bf16x8*)&Qt[(R0 + i * 16 + fr) * 136 + hh * 64 + ks * 32 + q * 8];
#pragma unroll
        for (int j = 0; j < 4; ++j) {
            bf16x8 b = *(const bf16x8*)&Wfs[hh * 4608 + (j * 16 + fr) * 72 + ks * 32 + q * 8];
#pragma unroll
            for (int i = 0; i < 2; ++i)
                z2[i][j] = __builtin_amdgcn_mfma_f32_16x16x32_bf16(a[i], b, z2[i][j], 0, 0, 0);
        }
    }

    // softmax over f per row, entirely in registers (16-lane quad groups)
    ushort* outp = (z == 0) ? fqB : fkB;
    const int hgl = 2 * bx + hh;
#pragma unroll
    for (int i = 0; i < 2; ++i)
#pragma unroll
        for (int r = 0; r < 4; ++r) {
            float m = z2[i][0][r];
#pragma unroll
            for (int j = 1; j < 4; ++j) m = fmaxf(m, z2[i][j][r]);
            m = fmaxf(m, __shfl_xor(m, 1)); m = fmaxf(m, __shfl_xor(m, 2));
            m = fmaxf(m, __shfl_xor(m, 4)); m = fmaxf(m, __shfl_xor(m, 8));
            float e4[4], s = 0.f;
#pragma unroll
            for (int j = 0; j < 4; ++j) { e4[j] = __expf(z2[i][j][r] - m); s += e4[j]; }
            s += __shfl_xor(s, 1); s += __shfl_xor(s, 2);
            s += __shfl_xor(s, 4); s += __shfl_xor(s, 8);
            const float inv = 1.0f / s;
            const int l = R0 + i * 16 + q * 4 + r;
            ushort* op = outp + ((size_t)hgl * LQ + l0 + l) * FDM;
#pragma unroll
            for (int j = 0; j < 4; ++j) op[j * 16 + ec] = f2b_raw(e4[j] * inv);
        }
}

// ---------------------------------------------------------------------------
// Convert: y=0..4 fp32->bf16 tensors; y=5,6 Wf transpose (h = blockIdx.x < 32)
// ---------------------------------------------------------------------------
struct ConvArgs {
    const float* src[5]; ushort* dst[5]; int n[5];
    const float* Wfq; const float* Wfk; ushort* WfqT; ushort* WfkT;
};
__global__ __launch_bounds__(256) void conv_all(ConvArgs p) {
    const int y = blockIdx.y, t = threadIdx.x;
    if (y < 5) {
        const int i = (blockIdx.x * 256 + t) * 4;
        if (i >= p.n[y]) return;
        float4 v = *(const float4*)&p.src[y][i];
        ushort4 o = make_ushort4(f2b_raw(v.x), f2b_raw(v.y), f2b_raw(v.z), f2b_raw(v.w));
        *(ushort4*)&p.dst[y][i] = o;
        return;
    }
    if (blockIdx.x >= NH) return;
    const int h = blockIdx.x;
    const float* src = ((y == 6) ? p.Wfk : p.Wfq) + (size_t)h * 4096;  // [d][f]
    ushort* dst = ((y == 6) ? p.WfkT : p.WfqT) + (size_t)h * 4096;     // [f][d]
    __shared__ float tile[64][65];
    for (int it = 0; it < 16; ++it) {
        int e = it * 256 + t; int d = e >> 6, f = e & 63;
        tile[d][f] = src[e];
    }
    __syncthreads();
    for (int it = 0; it < 16; ++it) {
        int e = it * 256 + t; int f = e >> 6, d = e & 63;
        dst[e] = f2b_raw(tile[d][f]);
    }
}

// ---------------------------------------------------------------------------
// Per-chunk KV state via MFMA: St[d][f] = sum_l VT[d][l]*fk[l][f]; Ks[f].
// grid (NCH, NH), block 256.
// ---------------------------------------------------------------------------
__global__ __launch_bounds__(256) void chunk_state(
    const ushort* __restrict__ fkB, const ushort* __restrict__ VTb,
    float* __restrict__ Sraw, float* __restrict__ Ks) {
    __shared__ __align__(16) ushort Vs[64 * 72];   // [d][l]
    __shared__ __align__(16) ushort Fs[64 * 72];   // [f][l]
    const int c = blockIdx.x, h = blockIdx.y;
    const int t = threadIdx.x, lane = t & 63, w = t >> 6;
    const int l0 = c * CT;
    const int fr = lane & 15, q = lane >> 4, ec = lane & 15;
    const size_t cb = ((size_t)h * NCH + c) * 4096;

    for (int it = 0; it < 2; ++it) {
        const int e = (it * 256 + t) * 8;
        const int row = e >> 6, col = e & 63;
        *(uint4*)&Vs[row * 72 + col] = *(const uint4*)&VTb[cb + e];
        uint4 fv = *(const uint4*)&fkB[((size_t)h * LQ + l0) * FDM + e];
        const ushort* pf = (const ushort*)&fv;
#pragma unroll
        for (int i2 = 0; i2 < 8; ++i2) Fs[(col + i2) * 72 + row] = pf[i2];
    }
    __syncthreads();

    f32x4 acc[4] = {};
#pragma unroll
    for (int ks = 0; ks < 2; ++ks) {
        bf16x8 a = *(const bf16x8*)&Vs[(w * 16 + fr) * 72 + ks * 32 + q * 8];
#pragma unroll
        for (int j = 0; j < 4; ++j) {
            bf16x8 b = *(const bf16x8*)&Fs[(j * 16 + fr) * 72 + ks * 32 + q * 8];
            acc[j] = __builtin_amdgcn_mfma_f32_16x16x32_bf16(a, b, acc[j], 0, 0, 0);
        }
    }
    float* sp = Sraw + cb;
#pragma unroll
    for (int j = 0; j < 4; ++j)
#pragma unroll
        for (int r = 0; r < 4; ++r)
            sp[(w * 16 + q * 4 + r) * 64 + j * 16 + ec] = acc[j][r];
    if (t < 64) {
        float s = 0.f;
#pragma unroll 8
        for (int l = 0; l < 64; ++l) s += b2f(Fs[t * 72 + l]);
        Ks[((size_t)h * NCH + c) * FDM + t] = s;
    }
}

// ---------------------------------------------------------------------------
// Exclusive prefix over chunks; grid (NH, 8), block 256.
// ---------------------------------------------------------------------------
__global__ __launch_bounds__(256) void prefix2(const float* __restrict__ Sraw,
                                               ushort* __restrict__ SpreB,
                                               const float* __restrict__ Ks,
                                               float* __restrict__ Kpre) {
    const int h = blockIdx.x, eb = blockIdx.y, t = threadIdx.x;
    const int e0 = eb * 512 + t * 2;
    float r0 = 0.f, r1 = 0.f;
    const size_t hb = (size_t)h * NCH * 4096;
    for (int c2 = 0; c2 < NCH; ++c2) {
        const size_t base = hb + (size_t)c2 * 4096 + e0;
        float c0 = Sraw[base], c1 = Sraw[base + 1];
        ushort2 o = make_ushort2(f2b_raw(r0), f2b_raw(r1));
        *(ushort2*)&SpreB[base] = o;
        r0 += c0; r1 += c1;
    }
    if (eb == 0 && t < 64) {
        float rk = 0.f;
        for (int c2 = 0; c2 < NCH; ++c2) {
            const size_t kb2 = ((size_t)h * NCH + c2) * FDM + t;
            float cur = Ks[kb2];
            Kpre[kb2] = rk;
            rk += cur;
        }
    }
}

// ---------------------------------------------------------------------------
// Intra-chunk attention via MFMA.
// ---------------------------------------------------------------------------
__global__ __launch_bounds__(256) void intra2(
    const ushort* __restrict__ fqB, const ushort* __restrict__ fkB,
    const ushort* __restrict__ VTb, const ushort* __restrict__ SpreB,
    const float* __restrict__ Kpre, ushort* __restrict__ Yb) {
    __shared__ __align__(16) ushort fqs[64 * 72];
    __shared__ __align__(16) ushort fks[64 * 72];
    __shared__ __align__(16) ushort VTs[64 * 72];
    __shared__ __align__(16) ushort Sps[64 * 72];
    __shared__ __align__(16) ushort Pms[64 * 72];
    __shared__ float den[64], kpr[64];

    const int c = blockIdx.x, h = blockIdx.y;
    const int t = threadIdx.x, lane = t & 63, wave = t >> 6;
    const int l0 = c * CT;
    const int fr = lane & 15, fo = (lane >> 4) * 8;
    const int g = lane >> 4, cc = lane & 15;

    const size_t qkbase = ((size_t)h * LQ + l0) * FDM;
    const size_t cbase  = ((size_t)h * NCH + c) * 4096;
    for (int it = 0; it < 2; ++it) {
        int e = (it * 256 + t) * 8;
        int row = e >> 6, col = e & 63;
        *(uint4*)&fqs[row * 72 + col] = *(const uint4*)&fqB[qkbase + e];
        *(uint4*)&fks[row * 72 + col] = *(const uint4*)&fkB[qkbase + e];
        *(uint4*)&VTs[row * 72 + col] = *(const uint4*)&VTb[cbase + e];
        *(uint4*)&Sps[row * 72 + col] = *(const uint4*)&SpreB[cbase + e];
    }
    if (t < 64) kpr[t] = Kpre[((size_t)h * NCH + c) * FDM + t];
    __syncthreads();

    // P = fq @ fk^T
    f32x4 accP[4] = {};
#pragma unroll
    for (int kp = 0; kp < 2; ++kp) {
        bf16x8 a = *(const bf16x8*)&fqs[(wave * 16 + fr) * 72 + kp * 32 + fo];
#pragma unroll
        for (int j = 0; j < 4; ++j) {
            bf16x8 b = *(const bf16x8*)&fks[(j * 16 + fr) * 72 + kp * 32 + fo];
            accP[j] = __builtin_amdgcn_mfma_f32_16x16x32_bf16(a, b, accP[j], 0, 0, 0);
        }
    }
#pragma unroll
    for (int j = 0; j < 4; ++j)
#pragma unroll
        for (int r = 0; r < 4; ++r) {
            int l = wave * 16 + g * 4 + r, lp = j * 16 + cc;
            Pms[l * 72 + lp] = (lp <= l) ? f2b_raw(accP[j][r]) : (ushort)0;
        }
    __syncthreads();

    // denominator, 4 threads/row
    {
        const int srow = t >> 2, spart = t & 3;
        float s = 0.f;
#pragma unroll
        for (int i = 0; i < 16; ++i) s += b2f(Pms[srow * 72 + spart * 16 + i]);
#pragma unroll
        for (int i = 0; i < 16; ++i) s += b2f(fqs[srow * 72 + spart * 16 + i]) * kpr[spart * 16 + i];
        s += __shfl_xor(s, 1); s += __shfl_xor(s, 2);
        if (spart == 0) den[srow] = s + EPSV;
    }
    __syncthreads();

    // Y = Pm @ V + fq @ Spre^T
    f32x4 accY[4] = {};
#pragma unroll
    for (int kp = 0; kp < 2; ++kp) {
        bf16x8 a = *(const bf16x8*)&Pms[(wave * 16 + fr) * 72 + kp * 32 + fo];
#pragma unroll
        for (int j = 0; j < 4; ++j) {
            bf16x8 b = *(const bf16x8*)&VTs[(j * 16 + fr) * 72 + kp * 32 + fo];
            accY[j] = __builtin_amdgcn_mfma_f32_16x16x32_bf16(a, b, accY[j], 0, 0, 0);
        }
    }
#pragma unroll
    for (int kp = 0; kp < 2; ++kp) {
        bf16x8 a = *(const bf16x8*)&fqs[(wave * 16 + fr) * 72 + kp * 32 + fo];
#pragma unroll
        for (int j = 0; j < 4; ++j) {
            bf16x8 b = *(const bf16x8*)&Sps[(j * 16 + fr) * 72 + kp * 32 + fo];
            accY[j] = __builtin_amdgcn_mfma_f32_16x16x32_bf16(a, b, accY[j], 0, 0, 0);
        }
    }
#pragma unroll
    for (int r = 0; r < 4; ++r) {
        int l = wave * 16 + g * 4 + r;
        float inv = 1.0f / den[l];
        ushort* yo = Yb + (size_t)(l0 + l) * HID + h * HDM;
#pragma unroll
        for (int j = 0; j < 4; ++j)
            yo[j * 16 + cc] = f2b_raw(accY[j][r] * inv);
    }
}

// ---------------------------------------------------------------------------
extern "C" void kernel_launch(void* const* d_in, const int* in_sizes, int n_in,
                              void* d_out, int out_size, void* d_ws, size_t ws_size,
                              hipStream_t stream) {
    const float* hs  = (const float*)d_in[0];
    const float* Wq  = (const float*)d_in[1];
    const float* Wk  = (const float*)d_in[2];
    const float* Wv  = (const float*)d_in[3];
    const float* Wo  = (const float*)d_in[4];
    const float* Wfq = (const float*)d_in[5];
    const float* Wfk = (const float*)d_in[6];
    float* out = (float*)d_out;

    const size_t SZ = (size_t)LQ * HID;          // 2,097,152
    const size_t WZ = (size_t)HID * HID;         // 4,194,304

    char* w = (char*)d_ws;
    auto aus = [&](size_t n) { ushort* p = (ushort*)w; w += n * sizeof(ushort); return p; };
    auto afl = [&](size_t n) { float*  p = (float*)w;  w += n * sizeof(float);  return p; };

    ushort* hsb   = aus(SZ);
    ushort* wqb   = aus(WZ);
    ushort* wkb   = aus(WZ);
    ushort* wvb   = aus(WZ);
    ushort* wob   = aus(WZ);
    ushort* fqB   = aus(SZ);
    ushort* fkB   = aus(SZ);
    ushort* VTb   = aus(SZ);
    ushort* WfqT  = aus((size_t)NH * 4096);
    ushort* WfkT  = aus((size_t)NH * 4096);
    ushort* SpreB = aus(SZ);
    ushort* Yb    = aus(SZ);
    float*  Sraw  = afl(SZ);
    float*  Ks    = afl((size_t)NH * NCH * FDM);
    float*  Kpre  = afl((size_t)NH * NCH * FDM);

    ConvArgs ca;
    ca.src[0] = hs; ca.dst[0] = hsb; ca.n[0] = (int)SZ;
    ca.src[1] = Wq; ca.dst[1] = wqb; ca.n[1] = (int)WZ;
    ca.src[2] = Wk; ca.dst[2] = wkb; ca.n[2] = (int)WZ;
    ca.src[3] = Wv; ca.dst[3] = wvb; ca.n[3] = (int)WZ;
    ca.src[4] = Wo; ca.dst[4] = wob; ca.n[4] = (int)WZ;
    ca.Wfq = Wfq; ca.Wfk = Wfk; ca.WfqT = WfqT; ca.WfkT = WfkT;
    conv_all<<<dim3((unsigned)(WZ / 1024), 7), 256, 0, stream>>>(ca);

    // 64x128 tiles: grid (16, 16, 3) = 768 blocks; z<2 fused feature map
    gemm_qkv_fm<<<dim3(HID / 128, LQ / 64, 3), 256, 0, stream>>>(
        hsb, wqb, wkb, wvb, WfqT, WfkT, fqB, fkB, VTb);

    chunk_state<<<dim3(NCH, NH), 256, 0, stream>>>(fkB, VTb, Sraw, Ks);

    prefix2<<<dim3(NH, 8), 256, 0, stream>>>(Sraw, SpreB, Ks, Kpre);

    intra2<<<dim3(NCH, NH), 256, 0, stream>>>(fqB, fkB, VTb, SpreB, Kpre, Yb);

    gemm_one<<<dim3(HID / 64, LQ / 64), 256, 0, stream>>>(Yb, wob, out);
}